// Round 6
// baseline (465.911 us; speedup 1.0000x reference)
//
#include <hip/hip_runtime.h>
#include <math.h>

#define NN 200000
#define NE 50000
#define D 128
#define ZROW 256   // zcat row: [o(128) | mem_new(128)] bf16

#define WGRU_SZ  196608   // 512*384 shorts
#define WATTN_SZ 147456   // 384*384
#define WLNK2_SZ 65536    // 128*512 shorts

#define CVT0 102528          // first idx of msgb conversion work in k_initprep
#define MSGB_V4 800000       // 50k*64/4

__device__ __forceinline__ float frcp_(float x) { return __builtin_amdgcn_rcpf(x); }
__device__ __forceinline__ float fsig_(float x) { return frcp_(1.f + __expf(-x)); }
__device__ __forceinline__ float ftanh_(float x) {
    float xc = fminf(fmaxf(x, -15.f), 15.f);
    float t = __expf(2.f * xc);
    return (t - 1.f) * frcp_(t + 1.f);
}

__device__ __forceinline__ unsigned short f2bf(float f) {
    unsigned int u = __float_as_uint(f);
    u = (u + 0x7fffu + ((u >> 16) & 1u)) >> 16;
    return (unsigned short)u;
}
__device__ __forceinline__ float bf2f(unsigned short b) {
    return __uint_as_float(((unsigned int)b) << 16);
}

typedef short bf16x8 __attribute__((ext_vector_type(8)));
typedef float f32x4  __attribute__((ext_vector_type(4)));

// ---------------- kernel 1: prep bf16 weights (replicated) + lastpos + msgb ---------
__global__ void k_initprep(const float* __restrict__ Wih, const float* __restrict__ Whh,
                           const float* __restrict__ Wk, const float* __restrict__ Wv,
                           const float* __restrict__ Wq, const float* __restrict__ We,
                           const float* __restrict__ Wskip, const float* __restrict__ bskip,
                           const float* __restrict__ Wls, const float* __restrict__ Wld,
                           const float* __restrict__ bls, const float* __restrict__ bld,
                           const int* __restrict__ src, const int* __restrict__ dst,
                           const float* __restrict__ msg,
                           unsigned short* __restrict__ wgru,
                           unsigned short* __restrict__ wattn,
                           unsigned short* __restrict__ wlink2,
                           float* __restrict__ blink,
                           unsigned short* __restrict__ msgb,
                           int* __restrict__ last_pos, int* __restrict__ count) {
    int idx = blockIdx.x * 256 + threadIdx.x;
    if (idx == 0) *count = 0;
    if (idx < 2 * NE) {                           // fused lastpos (pos+1 encoding)
        int id = (idx < NE) ? src[idx] : dst[idx - NE];
        atomicMax(&last_pos[id], idx + 1);
    }
    if (idx >= CVT0) {                            // dense msg -> bf16 stream
        int j = idx - CVT0;
        if (j < MSGB_V4) {
            float4 v = ((const float4*)msg)[j];
            ushort4 b;
            b.x = f2bf(v.x); b.y = f2bf(v.y); b.z = f2bf(v.z); b.w = f2bf(v.w);
            ((ushort4*)msgb)[j] = b;
        }
        return;
    }
    float4 v;
    unsigned short* dstp;
    int ncopies, stride;
    if (idx < 49152) {                            // gru
        int n = idx / 96;
        int c = (idx - n * 96) * 4;
        if (n < 384) {
            v = *(const float4*)&Wih[n * 384 + c];
            if (n < 256 && c < 128) {
                const float4 w2 = *(const float4*)&Whh[n * 128 + c];
                v.x += w2.x; v.y += w2.y; v.z += w2.z; v.w += w2.w;
            }
        } else {
            if (c >= 128) return;
            v = *(const float4*)&Whh[(n - 128) * 128 + c];
        }
        dstp = &wgru[n * 384 + c]; ncopies = 8; stride = WGRU_SZ;
    } else if (idx < 49152 + 36864) {             // attn
        int i2 = idx - 49152;
        int n = i2 / 96;
        int c = (i2 - n * 96) * 4;
        if (n < 256) {
            const float* Wm = (n < 128) ? Wk : Wv;
            int nn = n & 127;
            if (c < 128)       v = *(const float4*)&Wm[nn * 128 + c];
            else if (c < 256)  v = *(const float4*)&We[nn * 128 + (c - 128)];
            else return;
        } else {
            if (c < 256) return;
            v = *(const float4*)&Wq[(n - 256) * 128 + (c - 256)];
        }
        dstp = &wattn[n * 384 + c]; ncopies = 4; stride = WATTN_SZ;
    } else if (idx < 86016 + 8192) {              // linkA: direct Wls/Wld copies
        int i4 = idx - 86016;
        int n = i4 >> 6;
        int c = (i4 & 63) * 4;
        int dc;
        if (c < 128) { v = *(const float4*)&Wls[n * 128 + c];        dc = c; }
        else         { v = *(const float4*)&Wld[n * 128 + (c - 128)]; dc = c + 128; }
        dstp = &wlink2[n * 512 + dc]; ncopies = 4; stride = WLNK2_SZ;
    } else if (idx < 94208 + 8192) {              // linkB: Wc = W @ Wskip (f32 fold)
        int i5 = idx - 94208;
        int n = i5 >> 6;
        int g = i5 & 63;
        const float* Wrow = (g < 32) ? &Wls[n * 128] : &Wld[n * 128];
        int c = (g & 31) * 4;
        float ax = 0.f, ay = 0.f, az = 0.f, aw = 0.f;
        for (int j = 0; j < 128; ++j) {
            float a = Wrow[j];
            const float4 ws = *(const float4*)&Wskip[j * 128 + c];
            ax += a * ws.x; ay += a * ws.y; az += a * ws.z; aw += a * ws.w;
        }
        ushort4 b4;
        b4.x = f2bf(ax); b4.y = f2bf(ay); b4.z = f2bf(az); b4.w = f2bf(aw);
        unsigned short* dp = &wlink2[n * 512 + ((g < 32) ? 128 : 384) + c];
        for (int r = 0; r < 4; ++r)
            *(ushort4*)(dp + (size_t)r * WLNK2_SZ) = b4;
        return;
    } else {                                      // linkC: bias fold
        int n = idx - 102400;
        float s = bls[n] + bld[n];
        for (int j = 0; j < 128; ++j)
            s += (Wls[n * 128 + j] + Wld[n * 128 + j]) * bskip[j];
        blink[n] = s;
        return;
    }
    ushort4 b;
    b.x = f2bf(v.x); b.y = f2bf(v.y); b.z = f2bf(v.z); b.w = f2bf(v.w);
    for (int r = 0; r < ncopies; ++r)
        *(ushort4*)(dstp + (size_t)r * stride) = b;
}

// ---------------- kernel 2: compact (cheap) ---------------------------------------
__global__ void k_compact(const int* __restrict__ src, const int* __restrict__ dst,
                          const int* __restrict__ last_pos,
                          const float* __restrict__ tp, const float* __restrict__ lup,
                          int* __restrict__ count, int* __restrict__ node2slot,
                          int* __restrict__ head,
                          int4* __restrict__ slot_aux,
                          float* __restrict__ lu_new) {
    int i = blockIdx.x * blockDim.x + threadIdx.x;
    if (i >= 2 * NE) return;
    int e  = (i < NE) ? i : i - NE;
    int id = (i < NE) ? src[e] : dst[e];
    if (last_pos[id] != i + 1) return;             // pos+1 encoding
    int s = atomicAdd(count, 1);
    node2slot[id] = s;
    head[s] = -1;                                  // edge-list head init (slot owner)
    int oth = (i < NE) ? dst[e] : src[e];
    float tt = tp[e];
    float lu = lup[id];
    lu_new[id] = fmaxf(lu, tt);
    int4 aux; aux.x = e; aux.y = oth; aux.z = __float_as_int(tt - lu); aux.w = id;
    slot_aux[s] = aux;
}

// ---------------- kernel 2b: cooperative dedup'd memory->bf16 convert ---------------
// 8 lanes per slot: random 512B f32 read (memory[id], each unique row ONCE) ->
// dense coalesced bf16 write mco[slot]. Also resolves aux.y (oth node) -> oth SLOT
// (node2slot complete now), making k_gru's gathers single-hop.
__global__ __launch_bounds__(256) void k_memcvt(
    const float* __restrict__ memory, const int* __restrict__ node2slot,
    const int* __restrict__ countp,
    int4* __restrict__ slot_aux, unsigned short* __restrict__ mco)
{
    int cnt = *countp;
    int s = blockIdx.x * 32 + (threadIdx.x >> 3);
    if (s >= cnt) return;
    int li = threadIdx.x & 7;
    int4 aux = slot_aux[s];
    const float4* mrow = (const float4*)(memory + (size_t)aux.w * D);
    ushort4* orow = (ushort4*)(mco + (size_t)s * D);
    #pragma unroll
    for (int j = 0; j < 4; ++j) {
        float4 v = mrow[li + 8 * j];
        ushort4 b;
        b.x = f2bf(v.x); b.y = f2bf(v.y); b.z = f2bf(v.z); b.w = f2bf(v.w);
        orow[li + 8 * j] = b;
    }
    if (li == 0) slot_aux[s].y = node2slot[aux.y];   // oth node -> oth slot
}

// ---------------- kernel 3: GRU GEMM, GMB=32, 256 threads, 4 indep blocks/CU --------
// 128 regs/thread (64 acc + ~64 arch) -> 16 waves/CU; 4-wave blocks give 4
// INDEPENDENT blocks/CU (vs 2 with 512 threads) -> 2x independent gather phases.
// id row read DENSE from mco[ii]; oth row single-hop mco[oslot] (L3-hot 25MB).
#define GMB 32
__global__ __launch_bounds__(256) void k_gru(
    const unsigned short* __restrict__ msgb,
    const float* __restrict__ twp, const float* __restrict__ tbp,
    const int4* __restrict__ slot_aux,
    const unsigned short* __restrict__ mco,
    const unsigned short* __restrict__ wgru_all,
    const float* __restrict__ bih, const float* __restrict__ bhh,
    const int* __restrict__ countp,
    unsigned short* __restrict__ zcat)
{
    __shared__ alignas(16) unsigned short Xs[32][392];   // ~25 KB
    int cnt = *countp;
    int base = blockIdx.x * GMB;
    if (base >= cnt) return;
    int tid = threadIdx.x;
    const unsigned short* __restrict__ wgru = wgru_all + (size_t)(blockIdx.x & 7) * WGRU_SZ;

    {   // pack: 8 lanes per row, 32 rows
        int m = tid >> 3, li = tid & 7;
        int ii = base + m; if (ii >= cnt) ii = cnt - 1;   // tail dup (harmless)
        const int4 aux = slot_aux[ii];                    // dense 16B
        int e = aux.x, oslot = aux.y;
        float dt = __int_as_float(aux.z);
        const uint4* idr  = (const uint4*)(mco + (size_t)ii    * D);  // DENSE
        const uint4* othr = (const uint4*)(mco + (size_t)oslot * D);  // L3-hot random
        uint4 A0 = idr[li],  A1 = idr[li + 8];
        uint4 B0 = othr[li], B1 = othr[li + 8];
        uint4 M0 = *(const uint4*)&msgb[e * 64 + li * 8];
        int c0 = li * 8;
        float cv[8];
        #pragma unroll
        for (int k = 0; k < 8; ++k)
            cv[k] = cosf(dt * twp[c0 + k] + tbp[c0 + k]);
        *(uint4*)&Xs[m][li * 8]        = A0;
        *(uint4*)&Xs[m][64 + li * 8]   = A1;
        *(uint4*)&Xs[m][128 + li * 8]  = B0;
        *(uint4*)&Xs[m][192 + li * 8]  = B1;
        *(uint4*)&Xs[m][256 + li * 8]  = M0;
        ushort4 t0, t1;
        t0.x = f2bf(cv[0]); t0.y = f2bf(cv[1]); t0.z = f2bf(cv[2]); t0.w = f2bf(cv[3]);
        t1.x = f2bf(cv[4]); t1.y = f2bf(cv[5]); t1.z = f2bf(cv[6]); t1.w = f2bf(cv[7]);
        *(ushort4*)&Xs[m][320 + c0]     = t0;
        *(ushort4*)&Xs[m][320 + c0 + 4] = t1;
    }
    __syncthreads();

    int lane = tid & 63, w = tid >> 6;          // 4 waves
    int q = lane >> 4, l15 = lane & 15;
    int q8 = q * 8, w32 = w * 32;

    f32x4 acc[2][4][2];                          // [mt][gate][ns] = 64 regs
    #pragma unroll
    for (int mt = 0; mt < 2; ++mt)
        #pragma unroll
        for (int g = 0; g < 4; ++g)
            #pragma unroll
            for (int ns = 0; ns < 2; ++ns)
                acc[mt][g][ns] = (f32x4)(0.0f);

#define GRU_STEP(NG)                                                                      \
    {                                                                                     \
        bf16x8 a[2];                                                                      \
        _Pragma("unroll")                                                                 \
        for (int mt = 0; mt < 2; ++mt) a[mt] = *(const bf16x8*)&Xs[mt * 16 + l15][k0 + q8]; \
        _Pragma("unroll")                                                                 \
        for (int g = 0; g < NG; ++g) {                                                    \
            _Pragma("unroll")                                                             \
            for (int ns = 0; ns < 2; ++ns) {                                              \
                const bf16x8 b = *(const bf16x8*)&wgru[(g * 128 + w32 + ns * 16 + l15) * 384 + k0 + q8]; \
                _Pragma("unroll")                                                         \
                for (int mt = 0; mt < 2; ++mt)                                            \
                    acc[mt][g][ns] = __builtin_amdgcn_mfma_f32_16x16x32_bf16(a[mt], b, acc[mt][g][ns], 0, 0, 0); \
            }                                                                             \
        }                                                                                 \
    }

    #pragma unroll 2
    for (int ks = 0; ks < 4; ++ks) { int k0 = ks * 32; GRU_STEP(4) }
    #pragma unroll 2
    for (int ks = 4; ks < 12; ++ks) { int k0 = ks * 32; GRU_STEP(3) }
#undef GRU_STEP

    float nval[2][2][4];
    #pragma unroll
    for (int ns = 0; ns < 2; ++ns) {
        int c = w32 + ns * 16 + l15;
        float br  = bih[c]       + bhh[c];
        float bz  = bih[128 + c] + bhh[128 + c];
        float bin = bih[256 + c];
        float bhn = bhh[256 + c];
        #pragma unroll
        for (int mt = 0; mt < 2; ++mt) {
            #pragma unroll
            for (int reg = 0; reg < 4; ++reg) {
                int m = mt * 16 + q * 4 + reg;
                float r  = fsig_(acc[mt][0][ns][reg] + br);
                float zg = fsig_(acc[mt][1][ns][reg] + bz);
                float n  = ftanh_(acc[mt][2][ns][reg] + bin + r * (acc[mt][3][ns][reg] + bhn));
                float hv = bf2f(Xs[m][c]);
                nval[mt][ns][reg] = (1.f - zg) * n + zg * hv;
            }
        }
    }

    __syncthreads();
    #pragma unroll
    for (int ns = 0; ns < 2; ++ns) {
        int c = w32 + ns * 16 + l15;
        #pragma unroll
        for (int mt = 0; mt < 2; ++mt)
            #pragma unroll
            for (int reg = 0; reg < 4; ++reg)
                Xs[mt * 16 + q * 4 + reg][c] = f2bf(nval[mt][ns][reg]);
    }
    __syncthreads();

    {
        #pragma unroll
        for (int j = 0; j < 2; ++j) {
            int ch = tid + 256 * j;
            int m = ch >> 4, c8 = ch & 15;
            *(uint4*)&zcat[(size_t)(base + m) * ZROW + 128 + c8 * 8] =
                *(const uint4*)&Xs[m][c8 * 8];
        }
    }
}

// ---------------- kernel 5: attn k,v,q MFMA + logits -> dense per-edge a, a*v --------
#define AMB 32
__global__ __launch_bounds__(256) void k_attnA(
    const int* __restrict__ srcp, const int* __restrict__ dstp,
    const float* __restrict__ tp, const unsigned short* __restrict__ msgb,
    const float* __restrict__ twp, const float* __restrict__ tbp,
    const float* __restrict__ lu_new, const int* __restrict__ node2slot,
    const unsigned short* __restrict__ zcat,
    const unsigned short* __restrict__ wattn_all,
    const float* __restrict__ bq, const float* __restrict__ bk, const float* __restrict__ bv,
    unsigned short* __restrict__ vbuf, float* __restrict__ abuf,
    int* __restrict__ head, int* __restrict__ next)
{
    __shared__ alignas(16) unsigned short Xs[32][392];
    unsigned short (*kLb)[136] = (unsigned short(*)[136])(&Xs[0][0]);
    unsigned short (*qLb)[136] = (unsigned short(*)[136])(&Xs[0][0] + 4352);
    __shared__ float sa[AMB][2];
    __shared__ int sslot[AMB], sdslot[AMB];
    __shared__ float srel[AMB];
    int tid = threadIdx.x;
    int e0 = blockIdx.x * AMB;
    const unsigned short* __restrict__ wattn = wattn_all + (size_t)(blockIdx.x & 3) * WATTN_SZ;
    {   // fused edge-chain build (head inited in k_compact)
        int gid = blockIdx.x * 256 + tid;
        if (gid < NE) {
            int sl = node2slot[dstp[gid]];
            next[gid] = atomicExch(&head[sl], gid);
        }
    }
    if (tid < AMB) {
        int e = e0 + tid; if (e >= NE) e = NE - 1;
        int s = srcp[e], dd = dstp[e];
        sslot[tid]  = node2slot[s];
        sdslot[tid] = node2slot[dd];
        srel[tid] = lu_new[s] - tp[e];
    }
    __syncthreads();
    {
        int m = tid >> 3, li = tid & 7;
        int e = e0 + m; if (e >= NE) e = NE - 1;
        int ssl = sslot[m], dsl = sdslot[m];
        float rel = srel[m];
        uint4* xrow = (uint4*)&Xs[m][0];
        const uint4* srow = (const uint4*)&zcat[(size_t)ssl * ZROW + 128];
        const uint4* drow = (const uint4*)&zcat[(size_t)dsl * ZROW + 128];
        #pragma unroll
        for (int j = 0; j < 2; ++j) {
            xrow[li + 8 * j]      = srow[li + 8 * j];
            xrow[32 + li + 8 * j] = drow[li + 8 * j];
        }
        {
            int c0 = li * 8;
            ushort4 lo, hi;
            lo.x = f2bf(cosf(rel * twp[c0 + 0] + tbp[c0 + 0]));
            lo.y = f2bf(cosf(rel * twp[c0 + 1] + tbp[c0 + 1]));
            lo.z = f2bf(cosf(rel * twp[c0 + 2] + tbp[c0 + 2]));
            lo.w = f2bf(cosf(rel * twp[c0 + 3] + tbp[c0 + 3]));
            hi.x = f2bf(cosf(rel * twp[c0 + 4] + tbp[c0 + 4]));
            hi.y = f2bf(cosf(rel * twp[c0 + 5] + tbp[c0 + 5]));
            hi.z = f2bf(cosf(rel * twp[c0 + 6] + tbp[c0 + 6]));
            hi.w = f2bf(cosf(rel * twp[c0 + 7] + tbp[c0 + 7]));
            *(ushort4*)&Xs[m][128 + c0]     = lo;
            *(ushort4*)&Xs[m][128 + c0 + 4] = hi;
        }
        *(uint4*)&Xs[m][192 + li * 8] = *(const uint4*)&msgb[e * 64 + li * 8];
    }
    __syncthreads();

    int lane = tid & 63, w = tid >> 6;
    int q = lane >> 4, l15 = lane & 15;
    int q8 = q * 8;

    f32x4 acc[2][6];
    #pragma unroll
    for (int mt = 0; mt < 2; ++mt)
        #pragma unroll
        for (int jj = 0; jj < 6; ++jj) acc[mt][jj] = (f32x4)(0.0f);

    #pragma unroll 2
    for (int ks = 0; ks < 8; ++ks) {
        int k0 = ks * 32;
        const bf16x8 a0 = *(const bf16x8*)&Xs[l15][k0 + q8];
        const bf16x8 a1 = *(const bf16x8*)&Xs[16 + l15][k0 + q8];
        #pragma unroll
        for (int jj = 0; jj < 4; ++jj) {
            int nt = w + 4 * jj;
            const bf16x8 b = *(const bf16x8*)&wattn[(nt * 16 + l15) * 384 + k0 + q8];
            acc[0][jj] = __builtin_amdgcn_mfma_f32_16x16x32_bf16(a0, b, acc[0][jj], 0, 0, 0);
            acc[1][jj] = __builtin_amdgcn_mfma_f32_16x16x32_bf16(a1, b, acc[1][jj], 0, 0, 0);
        }
    }
    #pragma unroll 2
    for (int ks = 8; ks < 12; ++ks) {
        int k0 = ks * 32;
        const bf16x8 a0 = *(const bf16x8*)&Xs[l15][k0 + q8];
        const bf16x8 a1 = *(const bf16x8*)&Xs[16 + l15][k0 + q8];
        #pragma unroll
        for (int jj = 4; jj < 6; ++jj) {
            int nt = w + 4 * jj;
            const bf16x8 b = *(const bf16x8*)&wattn[(nt * 16 + l15) * 384 + k0 + q8];
            acc[0][jj] = __builtin_amdgcn_mfma_f32_16x16x32_bf16(a0, b, acc[0][jj], 0, 0, 0);
            acc[1][jj] = __builtin_amdgcn_mfma_f32_16x16x32_bf16(a1, b, acc[1][jj], 0, 0, 0);
        }
    }

    __syncthreads();    // Xs dead; kLb/qLb alias it — wait for all waves' K-loop reads

    float vreg[2][2][4];
    #pragma unroll
    for (int jj = 0; jj < 6; ++jj) {
        int nt = w + 4 * jj;
        int gate = nt >> 3;
        int ch = (nt & 7) * 16 + l15;
        float bias = (gate == 0) ? bk[ch] : (gate == 1) ? bv[ch] : bq[ch];
        #pragma unroll
        for (int mt = 0; mt < 2; ++mt)
            #pragma unroll
            for (int reg = 0; reg < 4; ++reg) {
                int m = mt * 16 + q * 4 + reg;
                float val = acc[mt][jj][reg] + bias;
                if (gate == 0)      kLb[m][ch] = f2bf(val);
                else if (gate == 2) qLb[m][ch] = f2bf(val);
                else                vreg[jj - 2][mt][reg] = val;
            }
    }
    __syncthreads();
    #pragma unroll
    for (int pr = 0; pr < 16; ++pr) {
        int p2 = pr * 4 + w;
        int m = p2 >> 1, h = p2 & 1;
        float prod = bf2f(qLb[m][h * 64 + lane]) * bf2f(kLb[m][h * 64 + lane]);
        #pragma unroll
        for (int off = 32; off; off >>= 1) prod += __shfl_down(prod, off);
        if (lane == 0) {
            float a = __expf(prod * 0.125f);
            sa[m][h] = a;
            if (e0 + m < NE) abuf[(e0 + m) * 2 + h] = a;
        }
    }
    __syncthreads();
    {
        unsigned short (*vL)[136] = qLb;
        #pragma unroll
        for (int jv = 0; jv < 2; ++jv) {
            int ch = w * 16 + jv * 64 + l15;
            int h = jv;
            #pragma unroll
            for (int mt = 0; mt < 2; ++mt)
                #pragma unroll
                for (int reg = 0; reg < 4; ++reg) {
                    int m = mt * 16 + q * 4 + reg;
                    vL[m][ch] = f2bf(sa[m][h] * vreg[jv][mt][reg]);
                }
        }
        __syncthreads();
        #pragma unroll
        for (int j = 0; j < 2; ++j) {
            int chunk = tid + 256 * j;
            int row = chunk >> 4, c8 = chunk & 15;
            if (e0 + row < NE)
                *(uint4*)&vbuf[(size_t)(e0 + row) * D + c8 * 8] = *(const uint4*)&vL[row][c8 * 8];
        }
    }
}

// ---------------- kernel 6: gather per-dst-slot edge lists, normalize -> o half -----
__global__ __launch_bounds__(256) void k_gather(
    const int* __restrict__ countp, const int* __restrict__ head,
    const int* __restrict__ next, const float* __restrict__ abuf,
    const unsigned short* __restrict__ vbuf, unsigned short* __restrict__ zcat)
{
    int cnt = *countp;
    int slot = blockIdx.x * 32 + (threadIdx.x >> 3);
    if (slot >= cnt) return;
    int li = threadIdx.x & 7;
    int c0 = li * 16;
    int h = li >> 2;
    float vsum[16];
    #pragma unroll
    for (int j = 0; j < 16; ++j) vsum[j] = 0.f;
    float asum = 0.f;
    for (int e = head[slot]; e != -1; e = next[e]) {
        asum += abuf[e * 2 + h];
        uint4 v0 = *(const uint4*)&vbuf[(size_t)e * D + c0];
        uint4 v1 = *(const uint4*)&vbuf[(size_t)e * D + c0 + 8];
        const unsigned short* pv0 = (const unsigned short*)&v0;
        const unsigned short* pv1 = (const unsigned short*)&v1;
        #pragma unroll
        for (int j = 0; j < 8; ++j) { vsum[j] += bf2f(pv0[j]); vsum[8 + j] += bf2f(pv1[j]); }
    }
    float rr = (asum > 0.f) ? frcp_(asum) : 0.f;
    unsigned short o[16];
    #pragma unroll
    for (int j = 0; j < 16; ++j) o[j] = f2bf(vsum[j] * rr);
    *(uint4*)&zcat[(size_t)slot * ZROW + c0]     = *(const uint4*)&o[0];
    *(uint4*)&zcat[(size_t)slot * ZROW + c0 + 8] = *(const uint4*)&o[8];
}

// ---------------- kernel 7: link predictor, K=512 folded GEMM, M=32 ------------------
#define ALB 32
__global__ __launch_bounds__(256) void k_link(
    const int* __restrict__ srcp, const int* __restrict__ dstp,
    const int* __restrict__ node2slot,
    const unsigned short* __restrict__ zcat,
    const unsigned short* __restrict__ wlink2_all,
    const float* __restrict__ blink,
    const float* __restrict__ Wlf, const float* __restrict__ blf,
    float* __restrict__ outp)
{
    __shared__ alignas(16) unsigned short Xs[32][520];   // 512 + 8 pad (~33 KB)
    __shared__ int ssl[32], sdl[32];
    __shared__ float sred[32][4];
    int tid = threadIdx.x;
    int e0 = blockIdx.x * ALB;
    const unsigned short* __restrict__ wlink2 = wlink2_all + (size_t)(blockIdx.x & 3) * WLNK2_SZ;
    if (tid < ALB) {
        int e = e0 + tid; if (e >= NE) e = NE - 1;
        ssl[tid] = node2slot[srcp[e]];
        sdl[tid] = node2slot[dstp[e]];
    }
    __syncthreads();
    {
        int m = tid >> 3, li = tid & 7;
        uint4* xrow = (uint4*)&Xs[m][0];
        const uint4* srow = (const uint4*)&zcat[(size_t)ssl[m] * ZROW];
        const uint4* drow = (const uint4*)&zcat[(size_t)sdl[m] * ZROW];
        #pragma unroll
        for (int j = 0; j < 4; ++j) {              // full 32 uint4 per endpoint row
            xrow[li + 8 * j]      = srow[li + 8 * j];
            xrow[32 + li + 8 * j] = drow[li + 8 * j];
        }
    }
    __syncthreads();

    int lane = tid & 63, w = tid >> 6;
    int q = lane >> 4, l15 = lane & 15;
    int q8 = q * 8;

    f32x4 acc[2][2];
    #pragma unroll
    for (int mt = 0; mt < 2; ++mt)
        #pragma unroll
        for (int jj = 0; jj < 2; ++jj) acc[mt][jj] = (f32x4)(0.0f);

    #pragma unroll 2
    for (int ks = 0; ks < 16; ++ks) {
        int k0 = ks * 32;
        bf16x8 a[2];
        #pragma unroll
        for (int mt = 0; mt < 2; ++mt) a[mt] = *(const bf16x8*)&Xs[mt * 16 + l15][k0 + q8];
        #pragma unroll
        for (int jj = 0; jj < 2; ++jj) {
            int nt = w + 4 * jj;
            const bf16x8 b = *(const bf16x8*)&wlink2[(nt * 16 + l15) * 512 + k0 + q8];
            #pragma unroll
            for (int mt = 0; mt < 2; ++mt)
                acc[mt][jj] = __builtin_amdgcn_mfma_f32_16x16x32_bf16(a[mt], b, acc[mt][jj], 0, 0, 0);
        }
    }

    float p[2][4];
    #pragma unroll
    for (int mt = 0; mt < 2; ++mt)
        #pragma unroll
        for (int reg = 0; reg < 4; ++reg) p[mt][reg] = 0.f;
    #pragma unroll
    for (int jj = 0; jj < 2; ++jj) {
        int ch = (w + 4 * jj) * 16 + l15;
        float bias = blink[ch];
        float wl = Wlf[ch];
        #pragma unroll
        for (int mt = 0; mt < 2; ++mt)
            #pragma unroll
            for (int reg = 0; reg < 4; ++reg)
                p[mt][reg] += fmaxf(acc[mt][jj][reg] + bias, 0.f) * wl;
    }
    #pragma unroll
    for (int mask = 1; mask < 16; mask <<= 1) {
        #pragma unroll
        for (int mt = 0; mt < 2; ++mt)
            #pragma unroll
            for (int reg = 0; reg < 4; ++reg)
                p[mt][reg] += __shfl_xor(p[mt][reg], mask);
    }
    if (l15 == 0) {
        #pragma unroll
        for (int mt = 0; mt < 2; ++mt)
            #pragma unroll
            for (int reg = 0; reg < 4; ++reg)
                sred[mt * 16 + q * 4 + reg][w] = p[mt][reg];
    }
    __syncthreads();
    if (tid < ALB) {
        int e = e0 + tid;
        if (e < NE)
            outp[e] = sred[tid][0] + sred[tid][1] + sred[tid][2] + sred[tid][3] + blf[0];
    }
}

extern "C" void kernel_launch(void* const* d_in, const int* in_sizes, int n_in,
                              void* d_out, int out_size, void* d_ws, size_t ws_size,
                              hipStream_t stream)
{
    const float* memory      = (const float*)d_in[0];
    const float* last_update = (const float*)d_in[1];
    const float* t           = (const float*)d_in[2];
    const float* msg         = (const float*)d_in[3];
    const int*   src         = (const int*)d_in[4];
    const int*   dst         = (const int*)d_in[5];
    const float* time_w      = (const float*)d_in[6];
    const float* time_b      = (const float*)d_in[7];
    const float* gru_Wih     = (const float*)d_in[8];
    const float* gru_bih     = (const float*)d_in[9];
    const float* gru_Whh     = (const float*)d_in[10];
    const float* gru_bhh     = (const float*)d_in[11];
    const float* Wq          = (const float*)d_in[12];
    const float* bq          = (const float*)d_in[13];
    const float* Wk          = (const float*)d_in[14];
    const float* bk          = (const float*)d_in[15];
    const float* Wv          = (const float*)d_in[16];
    const float* bv          = (const float*)d_in[17];
    const float* We          = (const float*)d_in[18];
    const float* Wskip       = (const float*)d_in[19];
    const float* bskip       = (const float*)d_in[20];
    const float* Wls         = (const float*)d_in[21];
    const float* bls         = (const float*)d_in[22];
    const float* Wld         = (const float*)d_in[23];
    const float* bld         = (const float*)d_in[24];
    const float* Wlf         = (const float*)d_in[25];
    const float* blf         = (const float*)d_in[26];
    float* outp = (float*)d_out;

    // workspace layout (bytes); R = 100,032 slots; weights replicated for L2 spread
    char* ws = (char*)d_ws;
    int*   last_pos  = (int*)  (ws + 0);               // N (pos+1 encoding, no init)
    int*   node2slot = (int*)  (ws + 800000);          // N
    float* lu_new    = (float*)(ws + 1600000);         // N
    int*   count     = (int*)  (ws + 2400000);         // 1 (+pad)
    unsigned short* wlink2  = (unsigned short*)(ws + 2800016);   // 4 x 128*512 bf16
    float* blink   = (float*)(ws + 3324304);           // 128 f32
    int4*  slot_aux = (int4*)(ws + 4000000);           // R x {e, oth->oslot, dt, id}
    unsigned short* mco     = (unsigned short*)(ws + 6000000);   // R*128 bf16 (by slot)
    unsigned short* msgb    = (unsigned short*)(ws + 57200000);  // 50k*64 bf16 (by edge)
    unsigned short* wgru    = (unsigned short*)(ws + 79624592);  // 8 x 512*384 bf16
    unsigned short* wattn   = (unsigned short*)(ws + 82770320);  // 4 x 384*384 bf16
    unsigned short* zcat    = (unsigned short*)(ws + 84474256);  // R*256 bf16 [o|mem]
    unsigned short* vbuf    = (unsigned short*)(ws + 135690640); // E*128 bf16 (by edge)
    float* abuf = (float*)(ws + 148490640);            // E*2 f32 (by edge)
    int*   head = (int*)  (ws + 148890640);            // R int (by slot)
    int*   next = (int*)  (ws + 149290768);            // E int (by edge)

    k_initprep<<<(CVT0 + MSGB_V4 + 255) / 256, 256, 0, stream>>>(
                 gru_Wih, gru_Whh, Wk, Wv, Wq, We, Wskip, bskip, Wls, Wld, bls, bld,
                 src, dst, msg, wgru, wattn, wlink2, blink, msgb, last_pos, count);
    k_compact <<<(2 * NE + 255) / 256, 256, 0, stream>>>(src, dst, last_pos,
                 t, last_update, count, node2slot, head, slot_aux, lu_new);
    k_memcvt  <<<(2 * NE + 31) / 32, 256, 0, stream>>>(memory, node2slot, count,
                 slot_aux, mco);
    k_gru     <<<(2 * NE + GMB - 1) / GMB, 256, 0, stream>>>(msgb, time_w, time_b,
                 slot_aux, mco, wgru, gru_bih, gru_bhh, count, zcat);
    k_attnA   <<<(NE + AMB - 1) / AMB, 256, 0, stream>>>(src, dst, t, msgb, time_w, time_b,
                 lu_new, node2slot, zcat, wattn, bq, bk, bv, vbuf, abuf, head, next);
    k_gather  <<<(2 * NE + 31) / 32, 256, 0, stream>>>(count, head, next, abuf, vbuf, zcat);
    k_link    <<<(NE + ALB - 1) / ALB, 256, 0, stream>>>(src, dst, node2slot, zcat,
                 wlink2, blink, Wlf, blf, outp);
}

// Round 7
// 403.222 us; speedup vs baseline: 1.1555x; 1.1555x over previous
//
#include <hip/hip_runtime.h>
#include <math.h>

#define NN 200000
#define NE 50000
#define D 128
#define ZROW 256   // zcat row: [o(128) | mem_new(128)] bf16

#define WGRU_SZ  196608   // 512*384 shorts
#define WATTN_SZ 147456   // 384*384
#define WLNK2_SZ 65536    // 128*512 shorts

#define CVT0 102528          // first idx of msgb conversion work in k_initprep
#define MSGB_V4 800000       // 50k*64/4

__device__ __forceinline__ float frcp_(float x) { return __builtin_amdgcn_rcpf(x); }
__device__ __forceinline__ float fsig_(float x) { return frcp_(1.f + __expf(-x)); }
__device__ __forceinline__ float ftanh_(float x) {
    float xc = fminf(fmaxf(x, -15.f), 15.f);
    float t = __expf(2.f * xc);
    return (t - 1.f) * frcp_(t + 1.f);
}

__device__ __forceinline__ unsigned short f2bf(float f) {
    unsigned int u = __float_as_uint(f);
    u = (u + 0x7fffu + ((u >> 16) & 1u)) >> 16;
    return (unsigned short)u;
}
__device__ __forceinline__ float bf2f(unsigned short b) {
    return __uint_as_float(((unsigned int)b) << 16);
}

typedef short bf16x8 __attribute__((ext_vector_type(8)));
typedef float f32x4  __attribute__((ext_vector_type(4)));

// ---------------- kernel 1: prep bf16 weights (replicated) + lastpos + msgb ---------
__global__ void k_initprep(const float* __restrict__ Wih, const float* __restrict__ Whh,
                           const float* __restrict__ Wk, const float* __restrict__ Wv,
                           const float* __restrict__ Wq, const float* __restrict__ We,
                           const float* __restrict__ Wskip, const float* __restrict__ bskip,
                           const float* __restrict__ Wls, const float* __restrict__ Wld,
                           const float* __restrict__ bls, const float* __restrict__ bld,
                           const int* __restrict__ src, const int* __restrict__ dst,
                           const float* __restrict__ msg,
                           unsigned short* __restrict__ wgru,
                           unsigned short* __restrict__ wattn,
                           unsigned short* __restrict__ wlink2,
                           float* __restrict__ blink,
                           unsigned short* __restrict__ msgb,
                           int* __restrict__ last_pos, int* __restrict__ count) {
    int idx = blockIdx.x * 256 + threadIdx.x;
    if (idx == 0) *count = 0;
    if (idx < 2 * NE) {                           // fused lastpos (pos+1 encoding)
        int id = (idx < NE) ? src[idx] : dst[idx - NE];
        atomicMax(&last_pos[id], idx + 1);
    }
    if (idx >= CVT0) {                            // dense msg -> bf16 stream
        int j = idx - CVT0;
        if (j < MSGB_V4) {
            float4 v = ((const float4*)msg)[j];
            ushort4 b;
            b.x = f2bf(v.x); b.y = f2bf(v.y); b.z = f2bf(v.z); b.w = f2bf(v.w);
            ((ushort4*)msgb)[j] = b;
        }
        return;
    }
    float4 v;
    unsigned short* dstp;
    int ncopies, stride;
    if (idx < 49152) {                            // gru
        int n = idx / 96;
        int c = (idx - n * 96) * 4;
        if (n < 384) {
            v = *(const float4*)&Wih[n * 384 + c];
            if (n < 256 && c < 128) {
                const float4 w2 = *(const float4*)&Whh[n * 128 + c];
                v.x += w2.x; v.y += w2.y; v.z += w2.z; v.w += w2.w;
            }
        } else {
            if (c >= 128) return;
            v = *(const float4*)&Whh[(n - 128) * 128 + c];
        }
        dstp = &wgru[n * 384 + c]; ncopies = 8; stride = WGRU_SZ;
    } else if (idx < 49152 + 36864) {             // attn
        int i2 = idx - 49152;
        int n = i2 / 96;
        int c = (i2 - n * 96) * 4;
        if (n < 256) {
            const float* Wm = (n < 128) ? Wk : Wv;
            int nn = n & 127;
            if (c < 128)       v = *(const float4*)&Wm[nn * 128 + c];
            else if (c < 256)  v = *(const float4*)&We[nn * 128 + (c - 128)];
            else return;
        } else {
            if (c < 256) return;
            v = *(const float4*)&Wq[(n - 256) * 128 + (c - 256)];
        }
        dstp = &wattn[n * 384 + c]; ncopies = 4; stride = WATTN_SZ;
    } else if (idx < 86016 + 8192) {              // linkA: direct Wls/Wld copies
        int i4 = idx - 86016;
        int n = i4 >> 6;
        int c = (i4 & 63) * 4;
        int dc;
        if (c < 128) { v = *(const float4*)&Wls[n * 128 + c];        dc = c; }
        else         { v = *(const float4*)&Wld[n * 128 + (c - 128)]; dc = c + 128; }
        dstp = &wlink2[n * 512 + dc]; ncopies = 4; stride = WLNK2_SZ;
    } else if (idx < 94208 + 8192) {              // linkB: Wc = W @ Wskip (f32 fold)
        int i5 = idx - 94208;
        int n = i5 >> 6;
        int g = i5 & 63;
        const float* Wrow = (g < 32) ? &Wls[n * 128] : &Wld[n * 128];
        int c = (g & 31) * 4;
        float ax = 0.f, ay = 0.f, az = 0.f, aw = 0.f;
        for (int j = 0; j < 128; ++j) {
            float a = Wrow[j];
            const float4 ws = *(const float4*)&Wskip[j * 128 + c];
            ax += a * ws.x; ay += a * ws.y; az += a * ws.z; aw += a * ws.w;
        }
        ushort4 b4;
        b4.x = f2bf(ax); b4.y = f2bf(ay); b4.z = f2bf(az); b4.w = f2bf(aw);
        unsigned short* dp = &wlink2[n * 512 + ((g < 32) ? 128 : 384) + c];
        for (int r = 0; r < 4; ++r)
            *(ushort4*)(dp + (size_t)r * WLNK2_SZ) = b4;
        return;
    } else {                                      // linkC: bias fold
        int n = idx - 102400;
        float s = bls[n] + bld[n];
        for (int j = 0; j < 128; ++j)
            s += (Wls[n * 128 + j] + Wld[n * 128 + j]) * bskip[j];
        blink[n] = s;
        return;
    }
    ushort4 b;
    b.x = f2bf(v.x); b.y = f2bf(v.y); b.z = f2bf(v.z); b.w = f2bf(v.w);
    for (int r = 0; r < ncopies; ++r)
        *(ushort4*)(dstp + (size_t)r * stride) = b;
}

// ---------------- kernel 2: compact (cheap) ---------------------------------------
__global__ void k_compact(const int* __restrict__ src, const int* __restrict__ dst,
                          const int* __restrict__ last_pos,
                          const float* __restrict__ tp, const float* __restrict__ lup,
                          int* __restrict__ count, int* __restrict__ node2slot,
                          int* __restrict__ head,
                          int4* __restrict__ slot_aux,
                          float* __restrict__ lu_new) {
    int i = blockIdx.x * blockDim.x + threadIdx.x;
    if (i >= 2 * NE) return;
    int e  = (i < NE) ? i : i - NE;
    int id = (i < NE) ? src[e] : dst[e];
    if (last_pos[id] != i + 1) return;             // pos+1 encoding
    int s = atomicAdd(count, 1);
    node2slot[id] = s;
    head[s] = -1;                                  // edge-list head init (slot owner)
    int oth = (i < NE) ? dst[e] : src[e];
    float tt = tp[e];
    float lu = lup[id];
    lu_new[id] = fmaxf(lu, tt);
    int4 aux; aux.x = e; aux.y = oth; aux.z = __float_as_int(tt - lu); aux.w = id;
    slot_aux[s] = aux;
}

// ---------------- kernel 2b: cooperative dedup'd memory->bf16 convert ---------------
// 8 lanes per slot: random 512B f32 read (memory[id], each unique row ONCE) ->
// dense coalesced bf16 write mco[slot]. Also resolves aux.y (oth node) -> oth SLOT.
__global__ __launch_bounds__(256) void k_memcvt(
    const float* __restrict__ memory, const int* __restrict__ node2slot,
    const int* __restrict__ countp,
    int4* __restrict__ slot_aux, unsigned short* __restrict__ mco)
{
    int cnt = *countp;
    int s = blockIdx.x * 32 + (threadIdx.x >> 3);
    if (s >= cnt) return;
    int li = threadIdx.x & 7;
    int4 aux = slot_aux[s];
    const float4* mrow = (const float4*)(memory + (size_t)aux.w * D);
    ushort4* orow = (ushort4*)(mco + (size_t)s * D);
    #pragma unroll
    for (int j = 0; j < 4; ++j) {
        float4 v = mrow[li + 8 * j];
        ushort4 b;
        b.x = f2bf(v.x); b.y = f2bf(v.y); b.z = f2bf(v.z); b.w = f2bf(v.w);
        orow[li + 8 * j] = b;
    }
    if (li == 0) slot_aux[s].y = node2slot[aux.y];   // oth node -> oth slot
}

// ---------------- kernel 3: GRU GEMM, GMB=64, 512 threads (proven best config) ------
// R6 ablation: GMB=32/256thr doubled time (weight amortization dominates). Back to
// 8-wave M=64 blocks; pack keeps R6's mco single-hop gather (dense id row).
#define GMB 64
__global__ __launch_bounds__(512) void k_gru(
    const unsigned short* __restrict__ msgb,
    const float* __restrict__ twp, const float* __restrict__ tbp,
    const int4* __restrict__ slot_aux,
    const unsigned short* __restrict__ mco,
    const unsigned short* __restrict__ wgru_all,
    const float* __restrict__ bih, const float* __restrict__ bhh,
    const int* __restrict__ countp,
    unsigned short* __restrict__ zcat)
{
    __shared__ alignas(16) unsigned short Xs[64][392];   // ~49 KB
    int cnt = *countp;
    int base = blockIdx.x * GMB;
    if (base >= cnt) return;
    int tid = threadIdx.x;
    const unsigned short* __restrict__ wgru = wgru_all + (size_t)(blockIdx.x & 7) * WGRU_SZ;

    {   // pack: 8 lanes per row, 64 rows
        int m = tid >> 3, li = tid & 7;
        int ii = base + m; if (ii >= cnt) ii = cnt - 1;   // tail dup (harmless)
        const int4 aux = slot_aux[ii];                    // dense 16B
        int e = aux.x, oslot = aux.y;
        float dt = __int_as_float(aux.z);
        const uint4* idr  = (const uint4*)(mco + (size_t)ii    * D);  // DENSE
        const uint4* othr = (const uint4*)(mco + (size_t)oslot * D);  // L3-hot random
        uint4 A0 = idr[li],  A1 = idr[li + 8];
        uint4 B0 = othr[li], B1 = othr[li + 8];
        uint4 M0 = *(const uint4*)&msgb[e * 64 + li * 8];
        int c0 = li * 8;
        float cv[8];
        #pragma unroll
        for (int k = 0; k < 8; ++k)
            cv[k] = cosf(dt * twp[c0 + k] + tbp[c0 + k]);
        *(uint4*)&Xs[m][li * 8]        = A0;
        *(uint4*)&Xs[m][64 + li * 8]   = A1;
        *(uint4*)&Xs[m][128 + li * 8]  = B0;
        *(uint4*)&Xs[m][192 + li * 8]  = B1;
        *(uint4*)&Xs[m][256 + li * 8]  = M0;
        ushort4 t0, t1;
        t0.x = f2bf(cv[0]); t0.y = f2bf(cv[1]); t0.z = f2bf(cv[2]); t0.w = f2bf(cv[3]);
        t1.x = f2bf(cv[4]); t1.y = f2bf(cv[5]); t1.z = f2bf(cv[6]); t1.w = f2bf(cv[7]);
        *(ushort4*)&Xs[m][320 + c0]     = t0;
        *(ushort4*)&Xs[m][320 + c0 + 4] = t1;
    }
    __syncthreads();

    int lane = tid & 63, w = tid >> 6;
    int q = lane >> 4, l15 = lane & 15;
    int q8 = q * 8, w16 = w * 16;

    f32x4 acc[4][4];
    #pragma unroll
    for (int mt = 0; mt < 4; ++mt)
        #pragma unroll
        for (int g = 0; g < 4; ++g)
            acc[mt][g] = (f32x4)(0.0f);

#define GRU_STEP(NG)                                                                      \
    {                                                                                     \
        bf16x8 a[4];                                                                      \
        _Pragma("unroll")                                                                 \
        for (int mt = 0; mt < 4; ++mt) a[mt] = *(const bf16x8*)&Xs[mt * 16 + l15][k0 + q8]; \
        _Pragma("unroll")                                                                 \
        for (int g = 0; g < NG; ++g) {                                                    \
            const bf16x8 b = *(const bf16x8*)&wgru[(g * 128 + w16 + l15) * 384 + k0 + q8]; \
            _Pragma("unroll")                                                             \
            for (int mt = 0; mt < 4; ++mt)                                                \
                acc[mt][g] = __builtin_amdgcn_mfma_f32_16x16x32_bf16(a[mt], b, acc[mt][g], 0, 0, 0); \
        }                                                                                 \
    }

    #pragma unroll 2
    for (int ks = 0; ks < 4; ++ks) { int k0 = ks * 32; GRU_STEP(4) }
    #pragma unroll 2
    for (int ks = 4; ks < 12; ++ks) { int k0 = ks * 32; GRU_STEP(3) }
#undef GRU_STEP

    float nval[4][4];
    {
        int c = w16 + l15;
        float br  = bih[c]       + bhh[c];
        float bz  = bih[128 + c] + bhh[128 + c];
        float bin = bih[256 + c];
        float bhn = bhh[256 + c];
        #pragma unroll
        for (int mt = 0; mt < 4; ++mt) {
            #pragma unroll
            for (int reg = 0; reg < 4; ++reg) {
                int m = mt * 16 + q * 4 + reg;
                float r  = fsig_(acc[mt][0][reg] + br);
                float zg = fsig_(acc[mt][1][reg] + bz);
                float n  = ftanh_(acc[mt][2][reg] + bin + r * (acc[mt][3][reg] + bhn));
                float hv = bf2f(Xs[m][c]);
                nval[mt][reg] = (1.f - zg) * n + zg * hv;
            }
        }
    }

    __syncthreads();
    {
        int c = w16 + l15;
        #pragma unroll
        for (int mt = 0; mt < 4; ++mt)
            #pragma unroll
            for (int reg = 0; reg < 4; ++reg)
                Xs[mt * 16 + q * 4 + reg][c] = f2bf(nval[mt][reg]);
    }
    __syncthreads();

    {
        #pragma unroll
        for (int j = 0; j < 2; ++j) {
            int ch = tid + 512 * j;
            int m = ch >> 4, c8 = ch & 15;
            *(uint4*)&zcat[(size_t)(base + m) * ZROW + 128 + c8 * 8] =
                *(const uint4*)&Xs[m][c8 * 8];
        }
    }
}

// ---------------- kernel 5: attn M=64, 512 threads (weight-amortization lever) ------
// Same lever as k_gru: 8-wave M=64 blocks halve per-edge weight traffic and block
// count vs M=32. Wave mapping: nt = w + 8*jj, so jj == gate (0=K,1=V,2=Q); each
// wave owns one 16-col output slice (ch = w*16+l15).
#define AMB 64
__global__ __launch_bounds__(512) void k_attnA(
    const int* __restrict__ srcp, const int* __restrict__ dstp,
    const float* __restrict__ tp, const unsigned short* __restrict__ msgb,
    const float* __restrict__ twp, const float* __restrict__ tbp,
    const float* __restrict__ lu_new, const int* __restrict__ node2slot,
    const unsigned short* __restrict__ zcat,
    const unsigned short* __restrict__ wattn_all,
    const float* __restrict__ bq, const float* __restrict__ bk, const float* __restrict__ bv,
    unsigned short* __restrict__ vbuf, float* __restrict__ abuf,
    int* __restrict__ head, int* __restrict__ next)
{
    __shared__ alignas(16) unsigned short Xs[64][392];        // 50,176 B
    unsigned short (*kLb)[136] = (unsigned short(*)[136])(&Xs[0][0]);           // 64x136
    unsigned short (*qLb)[136] = (unsigned short(*)[136])(&Xs[0][0] + 8704);    // 64x136
    __shared__ float sa[AMB][2];
    __shared__ int sslot[AMB], sdslot[AMB];
    __shared__ float srel[AMB];
    int tid = threadIdx.x;
    int e0 = blockIdx.x * AMB;
    const unsigned short* __restrict__ wattn = wattn_all + (size_t)(blockIdx.x & 3) * WATTN_SZ;
    {   // fused edge-chain build (head inited in k_compact)
        int gid = blockIdx.x * 512 + tid;
        if (gid < NE) {
            int sl = node2slot[dstp[gid]];
            next[gid] = atomicExch(&head[sl], gid);
        }
    }
    if (tid < AMB) {
        int e = e0 + tid; if (e >= NE) e = NE - 1;
        int s = srcp[e], dd = dstp[e];
        sslot[tid]  = node2slot[s];
        sdslot[tid] = node2slot[dd];
        srel[tid] = lu_new[s] - tp[e];
    }
    __syncthreads();
    {   // pack: 8 lanes/row, 64 rows: [src_mem | time_enc | msg | dst_mem]
        int m = tid >> 3, li = tid & 7;
        int e = e0 + m; if (e >= NE) e = NE - 1;
        int ssl = sslot[m], dsl = sdslot[m];
        float rel = srel[m];
        uint4* xrow = (uint4*)&Xs[m][0];
        const uint4* srow = (const uint4*)&zcat[(size_t)ssl * ZROW + 128];
        const uint4* drow = (const uint4*)&zcat[(size_t)dsl * ZROW + 128];
        #pragma unroll
        for (int j = 0; j < 2; ++j) {
            xrow[li + 8 * j]      = srow[li + 8 * j];
            xrow[32 + li + 8 * j] = drow[li + 8 * j];
        }
        {
            int c0 = li * 8;
            ushort4 lo, hi;
            lo.x = f2bf(cosf(rel * twp[c0 + 0] + tbp[c0 + 0]));
            lo.y = f2bf(cosf(rel * twp[c0 + 1] + tbp[c0 + 1]));
            lo.z = f2bf(cosf(rel * twp[c0 + 2] + tbp[c0 + 2]));
            lo.w = f2bf(cosf(rel * twp[c0 + 3] + tbp[c0 + 3]));
            hi.x = f2bf(cosf(rel * twp[c0 + 4] + tbp[c0 + 4]));
            hi.y = f2bf(cosf(rel * twp[c0 + 5] + tbp[c0 + 5]));
            hi.z = f2bf(cosf(rel * twp[c0 + 6] + tbp[c0 + 6]));
            hi.w = f2bf(cosf(rel * twp[c0 + 7] + tbp[c0 + 7]));
            *(ushort4*)&Xs[m][128 + c0]     = lo;
            *(ushort4*)&Xs[m][128 + c0 + 4] = hi;
        }
        *(uint4*)&Xs[m][192 + li * 8] = *(const uint4*)&msgb[e * 64 + li * 8];
    }
    __syncthreads();

    int lane = tid & 63, w = tid >> 6;          // 8 waves
    int q = lane >> 4, l15 = lane & 15;
    int q8 = q * 8;

    f32x4 acc[4][3];                             // [mt][gate]
    #pragma unroll
    for (int mt = 0; mt < 4; ++mt)
        #pragma unroll
        for (int jj = 0; jj < 3; ++jj) acc[mt][jj] = (f32x4)(0.0f);

    #pragma unroll 2
    for (int ks = 0; ks < 8; ++ks) {             // K,V gates consume X[0:256]
        int k0 = ks * 32;
        bf16x8 a[4];
        #pragma unroll
        for (int mt = 0; mt < 4; ++mt) a[mt] = *(const bf16x8*)&Xs[mt * 16 + l15][k0 + q8];
        #pragma unroll
        for (int jj = 0; jj < 2; ++jj) {
            int nt = w + 8 * jj;
            const bf16x8 b = *(const bf16x8*)&wattn[(nt * 16 + l15) * 384 + k0 + q8];
            #pragma unroll
            for (int mt = 0; mt < 4; ++mt)
                acc[mt][jj] = __builtin_amdgcn_mfma_f32_16x16x32_bf16(a[mt], b, acc[mt][jj], 0, 0, 0);
        }
    }
    #pragma unroll 2
    for (int ks = 8; ks < 12; ++ks) {            // Q gate consumes X[256:384]
        int k0 = ks * 32;
        bf16x8 a[4];
        #pragma unroll
        for (int mt = 0; mt < 4; ++mt) a[mt] = *(const bf16x8*)&Xs[mt * 16 + l15][k0 + q8];
        int nt = 16 + w;
        const bf16x8 b = *(const bf16x8*)&wattn[(nt * 16 + l15) * 384 + k0 + q8];
        #pragma unroll
        for (int mt = 0; mt < 4; ++mt)
            acc[mt][2] = __builtin_amdgcn_mfma_f32_16x16x32_bf16(a[mt], b, acc[mt][2], 0, 0, 0);
    }

    __syncthreads();    // Xs dead; kLb/qLb alias it — wait for all waves' K-loop reads

    float vreg[4][4];
    {
        int ch = w * 16 + l15;
        #pragma unroll
        for (int jj = 0; jj < 3; ++jj) {
            float bias = (jj == 0) ? bk[ch] : (jj == 1) ? bv[ch] : bq[ch];
            #pragma unroll
            for (int mt = 0; mt < 4; ++mt)
                #pragma unroll
                for (int reg = 0; reg < 4; ++reg) {
                    int m = mt * 16 + q * 4 + reg;
                    float val = acc[mt][jj][reg] + bias;
                    if (jj == 0)      kLb[m][ch] = f2bf(val);
                    else if (jj == 2) qLb[m][ch] = f2bf(val);
                    else              vreg[mt][reg] = val;
                }
        }
    }
    __syncthreads();
    #pragma unroll
    for (int pr = 0; pr < 16; ++pr) {            // 128 = 64 rows x 2 heads over 8 waves
        int p2 = pr * 8 + w;
        int m = p2 >> 1, h = p2 & 1;
        float prod = bf2f(qLb[m][h * 64 + lane]) * bf2f(kLb[m][h * 64 + lane]);
        #pragma unroll
        for (int off = 32; off; off >>= 1) prod += __shfl_down(prod, off);
        if (lane == 0) {
            float a = __expf(prod * 0.125f);
            sa[m][h] = a;
            if (e0 + m < NE) abuf[(e0 + m) * 2 + h] = a;
        }
    }
    __syncthreads();
    {
        unsigned short (*vL)[136] = qLb;         // qLb reads done (sync above)
        int ch = w * 16 + l15;
        int h = w >> 2;                          // this wave's head
        #pragma unroll
        for (int mt = 0; mt < 4; ++mt)
            #pragma unroll
            for (int reg = 0; reg < 4; ++reg) {
                int m = mt * 16 + q * 4 + reg;
                vL[m][ch] = f2bf(sa[m][h] * vreg[mt][reg]);
            }
        __syncthreads();
        #pragma unroll
        for (int j = 0; j < 2; ++j) {
            int chunk = tid + 512 * j;
            int row = chunk >> 4, c8 = chunk & 15;
            if (e0 + row < NE)
                *(uint4*)&vbuf[(size_t)(e0 + row) * D + c8 * 8] = *(const uint4*)&vL[row][c8 * 8];
        }
    }
}

// ---------------- kernel 6: gather per-dst-slot edge lists, normalize -> o half -----
__global__ __launch_bounds__(256) void k_gather(
    const int* __restrict__ countp, const int* __restrict__ head,
    const int* __restrict__ next, const float* __restrict__ abuf,
    const unsigned short* __restrict__ vbuf, unsigned short* __restrict__ zcat)
{
    int cnt = *countp;
    int slot = blockIdx.x * 32 + (threadIdx.x >> 3);
    if (slot >= cnt) return;
    int li = threadIdx.x & 7;
    int c0 = li * 16;
    int h = li >> 2;
    float vsum[16];
    #pragma unroll
    for (int j = 0; j < 16; ++j) vsum[j] = 0.f;
    float asum = 0.f;
    for (int e = head[slot]; e != -1; e = next[e]) {
        asum += abuf[e * 2 + h];
        uint4 v0 = *(const uint4*)&vbuf[(size_t)e * D + c0];
        uint4 v1 = *(const uint4*)&vbuf[(size_t)e * D + c0 + 8];
        const unsigned short* pv0 = (const unsigned short*)&v0;
        const unsigned short* pv1 = (const unsigned short*)&v1;
        #pragma unroll
        for (int j = 0; j < 8; ++j) { vsum[j] += bf2f(pv0[j]); vsum[8 + j] += bf2f(pv1[j]); }
    }
    float rr = (asum > 0.f) ? frcp_(asum) : 0.f;
    unsigned short o[16];
    #pragma unroll
    for (int j = 0; j < 16; ++j) o[j] = f2bf(vsum[j] * rr);
    *(uint4*)&zcat[(size_t)slot * ZROW + c0]     = *(const uint4*)&o[0];
    *(uint4*)&zcat[(size_t)slot * ZROW + c0 + 8] = *(const uint4*)&o[8];
}

// ---------------- kernel 7: link predictor, K=512 folded GEMM, M=32 ------------------
#define ALB 32
__global__ __launch_bounds__(256) void k_link(
    const int* __restrict__ srcp, const int* __restrict__ dstp,
    const int* __restrict__ node2slot,
    const unsigned short* __restrict__ zcat,
    const unsigned short* __restrict__ wlink2_all,
    const float* __restrict__ blink,
    const float* __restrict__ Wlf, const float* __restrict__ blf,
    float* __restrict__ outp)
{
    __shared__ alignas(16) unsigned short Xs[32][520];   // 512 + 8 pad (~33 KB)
    __shared__ int ssl[32], sdl[32];
    __shared__ float sred[32][4];
    int tid = threadIdx.x;
    int e0 = blockIdx.x * ALB;
    const unsigned short* __restrict__ wlink2 = wlink2_all + (size_t)(blockIdx.x & 3) * WLNK2_SZ;
    if (tid < ALB) {
        int e = e0 + tid; if (e >= NE) e = NE - 1;
        ssl[tid] = node2slot[srcp[e]];
        sdl[tid] = node2slot[dstp[e]];
    }
    __syncthreads();
    {
        int m = tid >> 3, li = tid & 7;
        uint4* xrow = (uint4*)&Xs[m][0];
        const uint4* srow = (const uint4*)&zcat[(size_t)ssl[m] * ZROW];
        const uint4* drow = (const uint4*)&zcat[(size_t)sdl[m] * ZROW];
        #pragma unroll
        for (int j = 0; j < 4; ++j) {              // full 32 uint4 per endpoint row
            xrow[li + 8 * j]      = srow[li + 8 * j];
            xrow[32 + li + 8 * j] = drow[li + 8 * j];
        }
    }
    __syncthreads();

    int lane = tid & 63, w = tid >> 6;
    int q = lane >> 4, l15 = lane & 15;
    int q8 = q * 8;

    f32x4 acc[2][2];
    #pragma unroll
    for (int mt = 0; mt < 2; ++mt)
        #pragma unroll
        for (int jj = 0; jj < 2; ++jj) acc[mt][jj] = (f32x4)(0.0f);

    #pragma unroll 2
    for (int ks = 0; ks < 16; ++ks) {
        int k0 = ks * 32;
        bf16x8 a[2];
        #pragma unroll
        for (int mt = 0; mt < 2; ++mt) a[mt] = *(const bf16x8*)&Xs[mt * 16 + l15][k0 + q8];
        #pragma unroll
        for (int jj = 0; jj < 2; ++jj) {
            int nt = w + 4 * jj;
            const bf16x8 b = *(const bf16x8*)&wlink2[(nt * 16 + l15) * 512 + k0 + q8];
            #pragma unroll
            for (int mt = 0; mt < 2; ++mt)
                acc[mt][jj] = __builtin_amdgcn_mfma_f32_16x16x32_bf16(a[mt], b, acc[mt][jj], 0, 0, 0);
        }
    }

    float p[2][4];
    #pragma unroll
    for (int mt = 0; mt < 2; ++mt)
        #pragma unroll
        for (int reg = 0; reg < 4; ++reg) p[mt][reg] = 0.f;
    #pragma unroll
    for (int jj = 0; jj < 2; ++jj) {
        int ch = (w + 4 * jj) * 16 + l15;
        float bias = blink[ch];
        float wl = Wlf[ch];
        #pragma unroll
        for (int mt = 0; mt < 2; ++mt)
            #pragma unroll
            for (int reg = 0; reg < 4; ++reg)
                p[mt][reg] += fmaxf(acc[mt][jj][reg] + bias, 0.f) * wl;
    }
    #pragma unroll
    for (int mask = 1; mask < 16; mask <<= 1) {
        #pragma unroll
        for (int mt = 0; mt < 2; ++mt)
            #pragma unroll
            for (int reg = 0; reg < 4; ++reg)
                p[mt][reg] += __shfl_xor(p[mt][reg], mask);
    }
    if (l15 == 0) {
        #pragma unroll
        for (int mt = 0; mt < 2; ++mt)
            #pragma unroll
            for (int reg = 0; reg < 4; ++reg)
                sred[mt * 16 + q * 4 + reg][w] = p[mt][reg];
    }
    __syncthreads();
    if (tid < ALB) {
        int e = e0 + tid;
        if (e < NE)
            outp[e] = sred[tid][0] + sred[tid][1] + sred[tid][2] + sred[tid][3] + blf[0];
    }
}

extern "C" void kernel_launch(void* const* d_in, const int* in_sizes, int n_in,
                              void* d_out, int out_size, void* d_ws, size_t ws_size,
                              hipStream_t stream)
{
    const float* memory      = (const float*)d_in[0];
    const float* last_update = (const float*)d_in[1];
    const float* t           = (const float*)d_in[2];
    const float* msg         = (const float*)d_in[3];
    const int*   src         = (const int*)d_in[4];
    const int*   dst         = (const int*)d_in[5];
    const float* time_w      = (const float*)d_in[6];
    const float* time_b      = (const float*)d_in[7];
    const float* gru_Wih     = (const float*)d_in[8];
    const float* gru_bih     = (const float*)d_in[9];
    const float* gru_Whh     = (const float*)d_in[10];
    const float* gru_bhh     = (const float*)d_in[11];
    const float* Wq          = (const float*)d_in[12];
    const float* bq          = (const float*)d_in[13];
    const float* Wk          = (const float*)d_in[14];
    const float* bk          = (const float*)d_in[15];
    const float* Wv          = (const float*)d_in[16];
    const float* bv          = (const float*)d_in[17];
    const float* We          = (const float*)d_in[18];
    const float* Wskip       = (const float*)d_in[19];
    const float* bskip       = (const float*)d_in[20];
    const float* Wls         = (const float*)d_in[21];
    const float* bls         = (const float*)d_in[22];
    const float* Wld         = (const float*)d_in[23];
    const float* bld         = (const float*)d_in[24];
    const float* Wlf         = (const float*)d_in[25];
    const float* blf         = (const float*)d_in[26];
    float* outp = (float*)d_out;

    // workspace layout (bytes); R = 100,032 slots; weights replicated for L2 spread
    char* ws = (char*)d_ws;
    int*   last_pos  = (int*)  (ws + 0);               // N (pos+1 encoding, no init)
    int*   node2slot = (int*)  (ws + 800000);          // N
    float* lu_new    = (float*)(ws + 1600000);         // N
    int*   count     = (int*)  (ws + 2400000);         // 1 (+pad)
    unsigned short* wlink2  = (unsigned short*)(ws + 2800016);   // 4 x 128*512 bf16
    float* blink   = (float*)(ws + 3324304);           // 128 f32
    int4*  slot_aux = (int4*)(ws + 4000000);           // R x {e, oth->oslot, dt, id}
    unsigned short* mco     = (unsigned short*)(ws + 6000000);   // R*128 bf16 (by slot)
    unsigned short* msgb    = (unsigned short*)(ws + 57200000);  // 50k*64 bf16 (by edge)
    unsigned short* wgru    = (unsigned short*)(ws + 79624592);  // 8 x 512*384 bf16
    unsigned short* wattn   = (unsigned short*)(ws + 82770320);  // 4 x 384*384 bf16
    unsigned short* zcat    = (unsigned short*)(ws + 84474256);  // R*256 bf16 [o|mem]
    unsigned short* vbuf    = (unsigned short*)(ws + 135690640); // E*128 bf16 (by edge)
    float* abuf = (float*)(ws + 148490640);            // E*2 f32 (by edge)
    int*   head = (int*)  (ws + 148890640);            // R int (by slot)
    int*   next = (int*)  (ws + 149290768);            // E int (by edge)

    k_initprep<<<(CVT0 + MSGB_V4 + 255) / 256, 256, 0, stream>>>(
                 gru_Wih, gru_Whh, Wk, Wv, Wq, We, Wskip, bskip, Wls, Wld, bls, bld,
                 src, dst, msg, wgru, wattn, wlink2, blink, msgb, last_pos, count);
    k_compact <<<(2 * NE + 255) / 256, 256, 0, stream>>>(src, dst, last_pos,
                 t, last_update, count, node2slot, head, slot_aux, lu_new);
    k_memcvt  <<<(2 * NE + 31) / 32, 256, 0, stream>>>(memory, node2slot, count,
                 slot_aux, mco);
    k_gru     <<<(2 * NE + GMB - 1) / GMB, 512, 0, stream>>>(msgb, time_w, time_b,
                 slot_aux, mco, wgru, gru_bih, gru_bhh, count, zcat);
    k_attnA   <<<(NE + AMB - 1) / AMB, 512, 0, stream>>>(src, dst, t, msgb, time_w, time_b,
                 lu_new, node2slot, zcat, wattn, bq, bk, bv, vbuf, abuf, head, next);
    k_gather  <<<(2 * NE + 31) / 32, 256, 0, stream>>>(count, head, next, abuf, vbuf, zcat);
    k_link    <<<(NE + ALB - 1) / ALB, 256, 0, stream>>>(src, dst, node2slot, zcat,
                 wlink2, blink, Wlf, blf, outp);
}

// Round 8
// 373.563 us; speedup vs baseline: 1.2472x; 1.0794x over previous
//
#include <hip/hip_runtime.h>
#include <math.h>

#define NN 200000
#define NE 50000
#define D 128

#define WGRU_SZ  196608   // 512*384 shorts
#define WATTN_SZ 147456   // 384*384
#define WSKP_SZ  16384    // 128*128
#define WLINK_SZ 32768    // 128*256

#define CVT0 98304           // first idx of msgb conversion work in k_initprep
#define MSGB_V4 800000       // 50k*64/4

__device__ __forceinline__ float frcp_(float x) { return __builtin_amdgcn_rcpf(x); }
__device__ __forceinline__ float fsig_(float x) { return frcp_(1.f + __expf(-x)); }
__device__ __forceinline__ float ftanh_(float x) {
    float xc = fminf(fmaxf(x, -15.f), 15.f);
    float t = __expf(2.f * xc);
    return (t - 1.f) * frcp_(t + 1.f);
}

__device__ __forceinline__ unsigned short f2bf(float f) {
    unsigned int u = __float_as_uint(f);
    u = (u + 0x7fffu + ((u >> 16) & 1u)) >> 16;
    return (unsigned short)u;
}
__device__ __forceinline__ float bf2f(unsigned short b) {
    return __uint_as_float(((unsigned int)b) << 16);
}

typedef short bf16x8 __attribute__((ext_vector_type(8)));
typedef float f32x4  __attribute__((ext_vector_type(4)));

// ---------------- kernel 1: prep bf16 weights (replicated) + lastpos + msgb ---------
__global__ void k_initprep(const float* __restrict__ Wih, const float* __restrict__ Whh,
                           const float* __restrict__ Wk, const float* __restrict__ Wv,
                           const float* __restrict__ Wq, const float* __restrict__ We,
                           const float* __restrict__ Wskip,
                           const float* __restrict__ Wls, const float* __restrict__ Wld,
                           const int* __restrict__ src, const int* __restrict__ dst,
                           const float* __restrict__ msg,
                           unsigned short* __restrict__ wgru,
                           unsigned short* __restrict__ wattn,
                           unsigned short* __restrict__ wskp,
                           unsigned short* __restrict__ wlink,
                           unsigned short* __restrict__ msgb,
                           int* __restrict__ last_pos, int* __restrict__ count) {
    int idx = blockIdx.x * 256 + threadIdx.x;
    if (idx == 0) *count = 0;
    if (idx < 2 * NE) {                           // fused lastpos (pos+1 encoding)
        int id = (idx < NE) ? src[idx] : dst[idx - NE];
        atomicMax(&last_pos[id], idx + 1);
    }
    if (idx >= CVT0) {                            // dense msg -> bf16 stream
        int j = idx - CVT0;
        if (j < MSGB_V4) {
            float4 v = ((const float4*)msg)[j];
            ushort4 b;
            b.x = f2bf(v.x); b.y = f2bf(v.y); b.z = f2bf(v.z); b.w = f2bf(v.w);
            ((ushort4*)msgb)[j] = b;
        }
        return;
    }
    float4 v;
    unsigned short* dstp;
    int ncopies, stride;
    if (idx < 49152) {                            // gru
        int n = idx / 96;
        int c = (idx - n * 96) * 4;
        if (n < 384) {
            v = *(const float4*)&Wih[n * 384 + c];
            if (n < 256 && c < 128) {
                const float4 w2 = *(const float4*)&Whh[n * 128 + c];
                v.x += w2.x; v.y += w2.y; v.z += w2.z; v.w += w2.w;
            }
        } else {
            if (c >= 128) return;
            v = *(const float4*)&Whh[(n - 128) * 128 + c];
        }
        dstp = &wgru[n * 384 + c]; ncopies = 8; stride = WGRU_SZ;
    } else if (idx < 49152 + 36864) {             // attn
        int i2 = idx - 49152;
        int n = i2 / 96;
        int c = (i2 - n * 96) * 4;
        if (n < 256) {
            const float* Wm = (n < 128) ? Wk : Wv;
            int nn = n & 127;
            if (c < 128)       v = *(const float4*)&Wm[nn * 128 + c];
            else if (c < 256)  v = *(const float4*)&We[nn * 128 + (c - 128)];
            else return;
        } else {
            if (c < 256) return;
            v = *(const float4*)&Wq[(n - 256) * 128 + (c - 256)];
        }
        dstp = &wattn[n * 384 + c]; ncopies = 4; stride = WATTN_SZ;
    } else if (idx < 49152 + 36864 + 4096) {      // skip
        int i3 = idx - 49152 - 36864;
        int n = i3 / 32;
        int c = (i3 - n * 32) * 4;
        v = *(const float4*)&Wskip[n * 128 + c];
        dstp = &wskp[n * 128 + c]; ncopies = 8; stride = WSKP_SZ;
    } else {                                      // link: [Wls | Wld]
        int i4 = idx - 49152 - 36864 - 4096;
        int n = i4 / 64;
        int c = (i4 - n * 64) * 4;
        if (c < 128) v = *(const float4*)&Wls[n * 128 + c];
        else         v = *(const float4*)&Wld[n * 128 + (c - 128)];
        dstp = &wlink[n * 256 + c]; ncopies = 4; stride = WLINK_SZ;
    }
    ushort4 b;
    b.x = f2bf(v.x); b.y = f2bf(v.y); b.z = f2bf(v.z); b.w = f2bf(v.w);
    for (int r = 0; r < ncopies; ++r)
        *(ushort4*)(dstp + (size_t)r * stride) = b;
}

// ---------------- kernel 2: compact (cheap) ---------------------------------------
__global__ void k_compact(const int* __restrict__ src, const int* __restrict__ dst,
                          const int* __restrict__ last_pos,
                          const float* __restrict__ tp, const float* __restrict__ lup,
                          int* __restrict__ count, int* __restrict__ node2slot,
                          int* __restrict__ head,
                          int4* __restrict__ slot_aux,
                          float* __restrict__ lu_new) {
    int i = blockIdx.x * blockDim.x + threadIdx.x;
    if (i >= 2 * NE) return;
    int e  = (i < NE) ? i : i - NE;
    int id = (i < NE) ? src[e] : dst[e];
    if (last_pos[id] != i + 1) return;             // pos+1 encoding
    int s = atomicAdd(count, 1);
    node2slot[id] = s;
    head[s] = -1;                                  // edge-list head init (slot owner)
    int oth = (i < NE) ? dst[e] : src[e];
    float tt = tp[e];
    float lu = lup[id];
    lu_new[id] = fmaxf(lu, tt);
    int4 aux; aux.x = e; aux.y = oth; aux.z = __float_as_int(tt - lu); aux.w = id;
    slot_aux[s] = aux;
}

// ---------------- kernel 3: GRU GEMM + skip GEMM, GMB=64, 512 threads ---------------
// R1-best structure: pack reads memory f32 directly (bf16 pre-pass not worth its
// producer cost), skip GEMM stays here (hidden under stalls: 105 vs 107 µs measured).
#define GMB 64
__global__ __launch_bounds__(512) void k_gru(
    const float* __restrict__ memp,
    const unsigned short* __restrict__ msgb,
    const float* __restrict__ twp, const float* __restrict__ tbp,
    const int4* __restrict__ slot_aux,
    const unsigned short* __restrict__ wgru_all,
    const float* __restrict__ bih, const float* __restrict__ bhh,
    const unsigned short* __restrict__ wskp_all, const float* __restrict__ bskip,
    const int* __restrict__ countp,
    unsigned short* __restrict__ mem_new, unsigned short* __restrict__ zbf)
{
    __shared__ alignas(16) unsigned short Xs[64][392];   // ~49 KB
    int cnt = *countp;
    int base = blockIdx.x * GMB;
    if (base >= cnt) return;
    int tid = threadIdx.x;
    const unsigned short* __restrict__ wgru = wgru_all + (size_t)(blockIdx.x & 7) * WGRU_SZ;
    const unsigned short* __restrict__ wskp = wskp_all + (size_t)(blockIdx.x & 7) * WSKP_SZ;

    {   // pack: 8 lanes per row, 64 rows; layout [id(128) | oth(128) | msg(64) | te(64)]
        int m = tid >> 3, li = tid & 7;
        int ii = base + m; if (ii >= cnt) ii = cnt - 1;   // tail dup (harmless)
        const int4 aux = slot_aux[ii];                    // dense 16B
        int e = aux.x, oth = aux.y, id = aux.w;
        float dt = __int_as_float(aux.z);
        const float4* idr  = (const float4*)(memp + (size_t)id  * D);
        const float4* othr = (const float4*)(memp + (size_t)oth * D);
        #pragma unroll
        for (int s4 = 0; s4 < 4; ++s4) {
            float4 v = idr[li + 8 * s4];
            ushort4 b;
            b.x = f2bf(v.x); b.y = f2bf(v.y); b.z = f2bf(v.z); b.w = f2bf(v.w);
            *(ushort4*)&Xs[m][(li + 8 * s4) * 4] = b;
            float4 v2 = othr[li + 8 * s4];
            ushort4 b2;
            b2.x = f2bf(v2.x); b2.y = f2bf(v2.y); b2.z = f2bf(v2.z); b2.w = f2bf(v2.w);
            *(ushort4*)&Xs[m][128 + (li + 8 * s4) * 4] = b2;
        }
        *(uint4*)&Xs[m][256 + li * 8] = *(const uint4*)&msgb[e * 64 + li * 8];
        int c0 = li * 8;
        float cv[8];
        #pragma unroll
        for (int k = 0; k < 8; ++k)
            cv[k] = cosf(dt * twp[c0 + k] + tbp[c0 + k]);
        ushort4 t0, t1;
        t0.x = f2bf(cv[0]); t0.y = f2bf(cv[1]); t0.z = f2bf(cv[2]); t0.w = f2bf(cv[3]);
        t1.x = f2bf(cv[4]); t1.y = f2bf(cv[5]); t1.z = f2bf(cv[6]); t1.w = f2bf(cv[7]);
        *(ushort4*)&Xs[m][320 + c0]     = t0;
        *(ushort4*)&Xs[m][320 + c0 + 4] = t1;
    }
    __syncthreads();

    int lane = tid & 63, w = tid >> 6;
    int q = lane >> 4, l15 = lane & 15;
    int q8 = q * 8, w16 = w * 16;

    f32x4 acc[4][4];
    #pragma unroll
    for (int mt = 0; mt < 4; ++mt)
        #pragma unroll
        for (int g = 0; g < 4; ++g)
            acc[mt][g] = (f32x4)(0.0f);

#define GRU_STEP(NG)                                                                      \
    {                                                                                     \
        bf16x8 a[4];                                                                      \
        _Pragma("unroll")                                                                 \
        for (int mt = 0; mt < 4; ++mt) a[mt] = *(const bf16x8*)&Xs[mt * 16 + l15][k0 + q8]; \
        _Pragma("unroll")                                                                 \
        for (int g = 0; g < NG; ++g) {                                                    \
            const bf16x8 b = *(const bf16x8*)&wgru[(g * 128 + w16 + l15) * 384 + k0 + q8]; \
            _Pragma("unroll")                                                             \
            for (int mt = 0; mt < 4; ++mt)                                                \
                acc[mt][g] = __builtin_amdgcn_mfma_f32_16x16x32_bf16(a[mt], b, acc[mt][g], 0, 0, 0); \
        }                                                                                 \
    }

    #pragma unroll 2
    for (int ks = 0; ks < 4; ++ks) { int k0 = ks * 32; GRU_STEP(4) }
    #pragma unroll 2
    for (int ks = 4; ks < 12; ++ks) { int k0 = ks * 32; GRU_STEP(3) }
#undef GRU_STEP

    float nval[4][4];
    {
        int c = w16 + l15;
        float br  = bih[c]       + bhh[c];
        float bz  = bih[128 + c] + bhh[128 + c];
        float bin = bih[256 + c];
        float bhn = bhh[256 + c];
        #pragma unroll
        for (int mt = 0; mt < 4; ++mt) {
            #pragma unroll
            for (int reg = 0; reg < 4; ++reg) {
                int m = mt * 16 + q * 4 + reg;
                float r  = fsig_(acc[mt][0][reg] + br);
                float zg = fsig_(acc[mt][1][reg] + bz);
                float n  = ftanh_(acc[mt][2][reg] + bin + r * (acc[mt][3][reg] + bhn));
                float hv = bf2f(Xs[m][c]);
                nval[mt][reg] = (1.f - zg) * n + zg * hv;
            }
        }
    }

    __syncthreads();
    {
        int c = w16 + l15;
        #pragma unroll
        for (int mt = 0; mt < 4; ++mt)
            #pragma unroll
            for (int reg = 0; reg < 4; ++reg)
                Xs[mt * 16 + q * 4 + reg][c] = f2bf(nval[mt][reg]);
    }
    __syncthreads();

    {
        #pragma unroll
        for (int j = 0; j < 2; ++j) {
            int ch = tid + 512 * j;
            int m = ch >> 4, c8 = ch & 15;
            *(uint4*)&mem_new[(size_t)(base + m) * D + c8 * 8] = *(const uint4*)&Xs[m][c8 * 8];
        }
    }

    f32x4 acc2[4];
    #pragma unroll
    for (int mt = 0; mt < 4; ++mt) acc2[mt] = (f32x4)(0.0f);
    #pragma unroll
    for (int ks = 0; ks < 4; ++ks) {
        int k0 = ks * 32;
        bf16x8 a[4];
        #pragma unroll
        for (int mt = 0; mt < 4; ++mt) a[mt] = *(const bf16x8*)&Xs[mt * 16 + l15][k0 + q8];
        const bf16x8 b = *(const bf16x8*)&wskp[(w16 + l15) * 128 + k0 + q8];
        #pragma unroll
        for (int mt = 0; mt < 4; ++mt)
            acc2[mt] = __builtin_amdgcn_mfma_f32_16x16x32_bf16(a[mt], b, acc2[mt], 0, 0, 0);
    }
    __syncthreads();
    {
        int ch = w16 + l15;
        float b = bskip[ch];
        #pragma unroll
        for (int mt = 0; mt < 4; ++mt)
            #pragma unroll
            for (int reg = 0; reg < 4; ++reg)
                Xs[mt * 16 + q * 4 + reg][ch] = f2bf(acc2[mt][reg] + b);
    }
    __syncthreads();
    {
        #pragma unroll
        for (int j = 0; j < 2; ++j) {
            int ch = tid + 512 * j;
            int m = ch >> 4, c8 = ch & 15;
            *(uint4*)&zbf[(size_t)(base + m) * D + c8 * 8] = *(const uint4*)&Xs[m][c8 * 8];
        }
    }
}

// ---------------- kernel 5: attn M=64, 512 threads (weight-amortization lever) ------
#define AMB 64
__global__ __launch_bounds__(512) void k_attnA(
    const int* __restrict__ srcp, const int* __restrict__ dstp,
    const float* __restrict__ tp, const unsigned short* __restrict__ msgb,
    const float* __restrict__ twp, const float* __restrict__ tbp,
    const float* __restrict__ lu_new, const int* __restrict__ node2slot,
    const unsigned short* __restrict__ mem_new,
    const unsigned short* __restrict__ wattn_all,
    const float* __restrict__ bq, const float* __restrict__ bk, const float* __restrict__ bv,
    unsigned short* __restrict__ vbuf, float* __restrict__ abuf,
    int* __restrict__ head, int* __restrict__ next)
{
    __shared__ alignas(16) unsigned short Xs[64][392];        // 50,176 B
    unsigned short (*kLb)[136] = (unsigned short(*)[136])(&Xs[0][0]);           // 64x136
    unsigned short (*qLb)[136] = (unsigned short(*)[136])(&Xs[0][0] + 8704);    // 64x136
    __shared__ float sa[AMB][2];
    __shared__ int sslot[AMB], sdslot[AMB];
    __shared__ float srel[AMB];
    int tid = threadIdx.x;
    int e0 = blockIdx.x * AMB;
    const unsigned short* __restrict__ wattn = wattn_all + (size_t)(blockIdx.x & 3) * WATTN_SZ;
    {   // fused edge-chain build (head inited in k_compact)
        int gid = blockIdx.x * 512 + tid;
        if (gid < NE) {
            int sl = node2slot[dstp[gid]];
            next[gid] = atomicExch(&head[sl], gid);
        }
    }
    if (tid < AMB) {
        int e = e0 + tid; if (e >= NE) e = NE - 1;
        int s = srcp[e], dd = dstp[e];
        sslot[tid]  = node2slot[s];
        sdslot[tid] = node2slot[dd];
        srel[tid] = lu_new[s] - tp[e];
    }
    __syncthreads();
    {   // pack: 8 lanes/row, 64 rows: [src_mem | time_enc | msg | dst_mem]
        int m = tid >> 3, li = tid & 7;
        int e = e0 + m; if (e >= NE) e = NE - 1;
        int ssl = sslot[m], dsl = sdslot[m];
        float rel = srel[m];
        uint4* xrow = (uint4*)&Xs[m][0];
        const uint4* srow = (const uint4*)&mem_new[(size_t)ssl * D];
        const uint4* drow = (const uint4*)&mem_new[(size_t)dsl * D];
        #pragma unroll
        for (int j = 0; j < 2; ++j) {
            xrow[li + 8 * j]      = srow[li + 8 * j];
            xrow[32 + li + 8 * j] = drow[li + 8 * j];
        }
        {
            int c0 = li * 8;
            ushort4 lo, hi;
            lo.x = f2bf(cosf(rel * twp[c0 + 0] + tbp[c0 + 0]));
            lo.y = f2bf(cosf(rel * twp[c0 + 1] + tbp[c0 + 1]));
            lo.z = f2bf(cosf(rel * twp[c0 + 2] + tbp[c0 + 2]));
            lo.w = f2bf(cosf(rel * twp[c0 + 3] + tbp[c0 + 3]));
            hi.x = f2bf(cosf(rel * twp[c0 + 4] + tbp[c0 + 4]));
            hi.y = f2bf(cosf(rel * twp[c0 + 5] + tbp[c0 + 5]));
            hi.z = f2bf(cosf(rel * twp[c0 + 6] + tbp[c0 + 6]));
            hi.w = f2bf(cosf(rel * twp[c0 + 7] + tbp[c0 + 7]));
            *(ushort4*)&Xs[m][128 + c0]     = lo;
            *(ushort4*)&Xs[m][128 + c0 + 4] = hi;
        }
        *(uint4*)&Xs[m][192 + li * 8] = *(const uint4*)&msgb[e * 64 + li * 8];
    }
    __syncthreads();

    int lane = tid & 63, w = tid >> 6;          // 8 waves
    int q = lane >> 4, l15 = lane & 15;
    int q8 = q * 8;

    f32x4 acc[4][3];                             // [mt][gate]
    #pragma unroll
    for (int mt = 0; mt < 4; ++mt)
        #pragma unroll
        for (int jj = 0; jj < 3; ++jj) acc[mt][jj] = (f32x4)(0.0f);

    #pragma unroll 2
    for (int ks = 0; ks < 8; ++ks) {             // K,V gates consume X[0:256]
        int k0 = ks * 32;
        bf16x8 a[4];
        #pragma unroll
        for (int mt = 0; mt < 4; ++mt) a[mt] = *(const bf16x8*)&Xs[mt * 16 + l15][k0 + q8];
        #pragma unroll
        for (int jj = 0; jj < 2; ++jj) {
            int nt = w + 8 * jj;
            const bf16x8 b = *(const bf16x8*)&wattn[(nt * 16 + l15) * 384 + k0 + q8];
            #pragma unroll
            for (int mt = 0; mt < 4; ++mt)
                acc[mt][jj] = __builtin_amdgcn_mfma_f32_16x16x32_bf16(a[mt], b, acc[mt][jj], 0, 0, 0);
        }
    }
    #pragma unroll 2
    for (int ks = 8; ks < 12; ++ks) {            // Q gate consumes X[256:384]
        int k0 = ks * 32;
        bf16x8 a[4];
        #pragma unroll
        for (int mt = 0; mt < 4; ++mt) a[mt] = *(const bf16x8*)&Xs[mt * 16 + l15][k0 + q8];
        int nt = 16 + w;
        const bf16x8 b = *(const bf16x8*)&wattn[(nt * 16 + l15) * 384 + k0 + q8];
        #pragma unroll
        for (int mt = 0; mt < 4; ++mt)
            acc[mt][2] = __builtin_amdgcn_mfma_f32_16x16x32_bf16(a[mt], b, acc[mt][2], 0, 0, 0);
    }

    __syncthreads();    // Xs dead; kLb/qLb alias it — wait for all waves' K-loop reads

    float vreg[4][4];
    {
        int ch = w * 16 + l15;
        #pragma unroll
        for (int jj = 0; jj < 3; ++jj) {
            float bias = (jj == 0) ? bk[ch] : (jj == 1) ? bv[ch] : bq[ch];
            #pragma unroll
            for (int mt = 0; mt < 4; ++mt)
                #pragma unroll
                for (int reg = 0; reg < 4; ++reg) {
                    int m = mt * 16 + q * 4 + reg;
                    float val = acc[mt][jj][reg] + bias;
                    if (jj == 0)      kLb[m][ch] = f2bf(val);
                    else if (jj == 2) qLb[m][ch] = f2bf(val);
                    else              vreg[mt][reg] = val;
                }
        }
    }
    __syncthreads();
    #pragma unroll
    for (int pr = 0; pr < 16; ++pr) {            // 128 = 64 rows x 2 heads over 8 waves
        int p2 = pr * 8 + w;
        int m = p2 >> 1, h = p2 & 1;
        float prod = bf2f(qLb[m][h * 64 + lane]) * bf2f(kLb[m][h * 64 + lane]);
        #pragma unroll
        for (int off = 32; off; off >>= 1) prod += __shfl_down(prod, off);
        if (lane == 0) {
            float a = __expf(prod * 0.125f);
            sa[m][h] = a;
            if (e0 + m < NE) abuf[(e0 + m) * 2 + h] = a;
        }
    }
    __syncthreads();
    {
        unsigned short (*vL)[136] = qLb;         // qLb reads done (sync above)
        int ch = w * 16 + l15;
        int h = w >> 2;                          // this wave's head
        #pragma unroll
        for (int mt = 0; mt < 4; ++mt)
            #pragma unroll
            for (int reg = 0; reg < 4; ++reg) {
                int m = mt * 16 + q * 4 + reg;
                vL[m][ch] = f2bf(sa[m][h] * vreg[mt][reg]);
            }
        __syncthreads();
        #pragma unroll
        for (int j = 0; j < 2; ++j) {
            int chunk = tid + 512 * j;
            int row = chunk >> 4, c8 = chunk & 15;
            if (e0 + row < NE)
                *(uint4*)&vbuf[(size_t)(e0 + row) * D + c8 * 8] = *(const uint4*)&vL[row][c8 * 8];
        }
    }
}

// ---------------- kernel 6: gather per-dst-slot edge lists, normalize, z += ----------
__global__ __launch_bounds__(256) void k_gather(
    const int* __restrict__ countp, const int* __restrict__ head,
    const int* __restrict__ next, const float* __restrict__ abuf,
    const unsigned short* __restrict__ vbuf, unsigned short* __restrict__ zbf)
{
    int cnt = *countp;
    int slot = blockIdx.x * 32 + (threadIdx.x >> 3);
    if (slot >= cnt) return;
    int li = threadIdx.x & 7;
    int c0 = li * 16;
    int h = li >> 2;
    float vsum[16];
    #pragma unroll
    for (int j = 0; j < 16; ++j) vsum[j] = 0.f;
    float asum = 0.f;
    for (int e = head[slot]; e != -1; e = next[e]) {
        asum += abuf[e * 2 + h];
        uint4 v0 = *(const uint4*)&vbuf[(size_t)e * D + c0];
        uint4 v1 = *(const uint4*)&vbuf[(size_t)e * D + c0 + 8];
        const unsigned short* pv0 = (const unsigned short*)&v0;
        const unsigned short* pv1 = (const unsigned short*)&v1;
        #pragma unroll
        for (int j = 0; j < 8; ++j) { vsum[j] += bf2f(pv0[j]); vsum[8 + j] += bf2f(pv1[j]); }
    }
    if (asum > 0.f) {
        float rr = frcp_(asum);
        uint4 z0 = *(const uint4*)&zbf[(size_t)slot * D + c0];
        uint4 z1 = *(const uint4*)&zbf[(size_t)slot * D + c0 + 8];
        const unsigned short* pz0 = (const unsigned short*)&z0;
        const unsigned short* pz1 = (const unsigned short*)&z1;
        unsigned short o[16];
        #pragma unroll
        for (int j = 0; j < 8; ++j) {
            o[j]     = f2bf(bf2f(pz0[j]) + vsum[j] * rr);
            o[8 + j] = f2bf(bf2f(pz1[j]) + vsum[8 + j] * rr);
        }
        *(uint4*)&zbf[(size_t)slot * D + c0]     = *(const uint4*)&o[0];
        *(uint4*)&zbf[(size_t)slot * D + c0 + 8] = *(const uint4*)&o[8];
    }
}

// ---------------- kernel 7: link predictor, K=256, M=32 (R1-best config) -------------
#define ALB 32
__global__ __launch_bounds__(256) void k_link(
    const int* __restrict__ srcp, const int* __restrict__ dstp,
    const int* __restrict__ node2slot,
    const unsigned short* __restrict__ zbf,
    const unsigned short* __restrict__ wlink_all,
    const float* __restrict__ bls, const float* __restrict__ bld,
    const float* __restrict__ Wlf, const float* __restrict__ blf,
    float* __restrict__ outp)
{
    __shared__ alignas(16) unsigned short Xs[32][264];
    __shared__ int ssl[32], sdl[32];
    __shared__ float sred[32][4];
    int tid = threadIdx.x;
    int e0 = blockIdx.x * ALB;
    const unsigned short* __restrict__ wlink = wlink_all + (size_t)(blockIdx.x & 3) * WLINK_SZ;
    if (tid < ALB) {
        int e = e0 + tid; if (e >= NE) e = NE - 1;
        ssl[tid] = node2slot[srcp[e]];
        sdl[tid] = node2slot[dstp[e]];
    }
    __syncthreads();
    {
        int m = tid >> 3, li = tid & 7;
        uint4* xrow = (uint4*)&Xs[m][0];
        const uint4* srow = (const uint4*)&zbf[(size_t)ssl[m] * D];
        const uint4* drow = (const uint4*)&zbf[(size_t)sdl[m] * D];
        xrow[li]      = srow[li];
        xrow[li + 8]  = srow[li + 8];
        xrow[16 + li] = drow[li];
        xrow[24 + li] = drow[li + 8];
    }
    __syncthreads();

    int lane = tid & 63, w = tid >> 6;
    int q = lane >> 4, l15 = lane & 15;
    int q8 = q * 8;

    f32x4 acc[2][2];
    #pragma unroll
    for (int mt = 0; mt < 2; ++mt)
        #pragma unroll
        for (int jj = 0; jj < 2; ++jj) acc[mt][jj] = (f32x4)(0.0f);

    #pragma unroll
    for (int ks = 0; ks < 8; ++ks) {
        int k0 = ks * 32;
        const bf16x8 a0 = *(const bf16x8*)&Xs[l15][k0 + q8];
        const bf16x8 a1 = *(const bf16x8*)&Xs[16 + l15][k0 + q8];
        #pragma unroll
        for (int jj = 0; jj < 2; ++jj) {
            int nt = w + 4 * jj;
            const bf16x8 b = *(const bf16x8*)&wlink[(nt * 16 + l15) * 256 + k0 + q8];
            acc[0][jj] = __builtin_amdgcn_mfma_f32_16x16x32_bf16(a0, b, acc[0][jj], 0, 0, 0);
            acc[1][jj] = __builtin_amdgcn_mfma_f32_16x16x32_bf16(a1, b, acc[1][jj], 0, 0, 0);
        }
    }

    float p[2][4];
    #pragma unroll
    for (int mt = 0; mt < 2; ++mt)
        #pragma unroll
        for (int reg = 0; reg < 4; ++reg) p[mt][reg] = 0.f;
    #pragma unroll
    for (int jj = 0; jj < 2; ++jj) {
        int ch = (w + 4 * jj) * 16 + l15;
        float bias = bls[ch] + bld[ch];
        float wl = Wlf[ch];
        #pragma unroll
        for (int mt = 0; mt < 2; ++mt)
            #pragma unroll
            for (int reg = 0; reg < 4; ++reg)
                p[mt][reg] += fmaxf(acc[mt][jj][reg] + bias, 0.f) * wl;
    }
    #pragma unroll
    for (int mask = 1; mask < 16; mask <<= 1) {
        #pragma unroll
        for (int mt = 0; mt < 2; ++mt)
            #pragma unroll
            for (int reg = 0; reg < 4; ++reg)
                p[mt][reg] += __shfl_xor(p[mt][reg], mask);
    }
    if (l15 == 0) {
        #pragma unroll
        for (int mt = 0; mt < 2; ++mt)
            #pragma unroll
            for (int reg = 0; reg < 4; ++reg)
                sred[mt * 16 + q * 4 + reg][w] = p[mt][reg];
    }
    __syncthreads();
    if (tid < ALB) {
        int e = e0 + tid;
        if (e < NE)
            outp[e] = sred[tid][0] + sred[tid][1] + sred[tid][2] + sred[tid][3] + blf[0];
    }
}

extern "C" void kernel_launch(void* const* d_in, const int* in_sizes, int n_in,
                              void* d_out, int out_size, void* d_ws, size_t ws_size,
                              hipStream_t stream)
{
    const float* memory      = (const float*)d_in[0];
    const float* last_update = (const float*)d_in[1];
    const float* t           = (const float*)d_in[2];
    const float* msg         = (const float*)d_in[3];
    const int*   src         = (const int*)d_in[4];
    const int*   dst         = (const int*)d_in[5];
    const float* time_w      = (const float*)d_in[6];
    const float* time_b      = (const float*)d_in[7];
    const float* gru_Wih     = (const float*)d_in[8];
    const float* gru_bih     = (const float*)d_in[9];
    const float* gru_Whh     = (const float*)d_in[10];
    const float* gru_bhh     = (const float*)d_in[11];
    const float* Wq          = (const float*)d_in[12];
    const float* bq          = (const float*)d_in[13];
    const float* Wk          = (const float*)d_in[14];
    const float* bk          = (const float*)d_in[15];
    const float* Wv          = (const float*)d_in[16];
    const float* bv          = (const float*)d_in[17];
    const float* We          = (const float*)d_in[18];
    const float* Wskip       = (const float*)d_in[19];
    const float* bskip       = (const float*)d_in[20];
    const float* Wls         = (const float*)d_in[21];
    const float* bls         = (const float*)d_in[22];
    const float* Wld         = (const float*)d_in[23];
    const float* bld         = (const float*)d_in[24];
    const float* Wlf         = (const float*)d_in[25];
    const float* blf         = (const float*)d_in[26];
    float* outp = (float*)d_out;

    // workspace layout (bytes); R = 100,032 slots; weights replicated for L2 spread
    char* ws = (char*)d_ws;
    int*   last_pos  = (int*)  (ws + 0);               // N (pos+1 encoding, no init)
    int*   node2slot = (int*)  (ws + 800000);          // N
    float* lu_new    = (float*)(ws + 1600000);         // N
    int*   count     = (int*)  (ws + 2400000);         // 1 (+pad)
    int4*  slot_aux  = (int4*) (ws + 2400016);         // R x {e, oth, dt, id}
    unsigned short* msgb    = (unsigned short*)(ws + 4000528);   // 50k*64 bf16
    unsigned short* wgru    = (unsigned short*)(ws + 10400528);  // 8 x 512*384 bf16
    unsigned short* wattn   = (unsigned short*)(ws + 13546256);  // 4 x 384*384 bf16
    unsigned short* wskp    = (unsigned short*)(ws + 14725904);  // 8 x 128*128 bf16
    unsigned short* wlink   = (unsigned short*)(ws + 14988048);  // 4 x 128*256 bf16
    unsigned short* mem_new = (unsigned short*)(ws + 15250192);  // R*128 bf16 (by slot)
    unsigned short* zbf     = (unsigned short*)(ws + 40858384);  // R*128 bf16 (by slot)
    unsigned short* vbuf    = (unsigned short*)(ws + 66466576);  // E*128 bf16 (by edge)
    float* abuf = (float*)(ws + 79266576);             // E*2 f32 (by edge)
    int*   head = (int*)  (ws + 79666576);             // R int (by slot)
    int*   next = (int*)  (ws + 80066704);             // E int (by edge)

    k_initprep<<<(CVT0 + MSGB_V4 + 255) / 256, 256, 0, stream>>>(
                 gru_Wih, gru_Whh, Wk, Wv, Wq, We, Wskip, Wls, Wld, src, dst, msg,
                 wgru, wattn, wskp, wlink, msgb, last_pos, count);
    k_compact <<<(2 * NE + 255) / 256, 256, 0, stream>>>(src, dst, last_pos,
                 t, last_update, count, node2slot, head, slot_aux, lu_new);
    k_gru     <<<(2 * NE + GMB - 1) / GMB, 512, 0, stream>>>(memory, msgb, time_w, time_b,
                 slot_aux, wgru, gru_bih, gru_bhh, wskp, bskip, count, mem_new, zbf);
    k_attnA   <<<(NE + AMB - 1) / AMB, 512, 0, stream>>>(src, dst, t, msgb, time_w, time_b,
                 lu_new, node2slot, mem_new, wattn, bq, bk, bv, vbuf, abuf, head, next);
    k_gather  <<<(2 * NE + 31) / 32, 256, 0, stream>>>(count, head, next, abuf, vbuf, zbf);
    k_link    <<<(NE + ALB - 1) / ALB, 256, 0, stream>>>(src, dst, node2slot, zbf,
                 wlink, bls, bld, Wlf, blf, outp);
}

// Round 10
// 369.152 us; speedup vs baseline: 1.2621x; 1.0120x over previous
//
#include <hip/hip_runtime.h>
#include <math.h>

#define NN 200000
#define NE 50000
#define D 128

#define WGRU_SZ  196608   // 512*384 shorts
#define WATTN_SZ 147456   // 384*384
#define WSKP_SZ  16384    // 128*128
#define WLINK_SZ 32768    // 128*256

#define CVT0 98304           // first idx of msgb conversion work in k_initprep
#define MSGB_V4 800000       // 50k*64/4

__device__ __forceinline__ float frcp_(float x) { return __builtin_amdgcn_rcpf(x); }
__device__ __forceinline__ float fsig_(float x) { return frcp_(1.f + __expf(-x)); }
__device__ __forceinline__ float ftanh_(float x) {
    float xc = fminf(fmaxf(x, -15.f), 15.f);
    float t = __expf(2.f * xc);
    return (t - 1.f) * frcp_(t + 1.f);
}

__device__ __forceinline__ unsigned short f2bf(float f) {
    unsigned int u = __float_as_uint(f);
    u = (u + 0x7fffu + ((u >> 16) & 1u)) >> 16;
    return (unsigned short)u;
}
__device__ __forceinline__ float bf2f(unsigned short b) {
    return __uint_as_float(((unsigned int)b) << 16);
}

typedef short bf16x8 __attribute__((ext_vector_type(8)));
typedef float f32x4  __attribute__((ext_vector_type(4)));

// ---------------- kernel 1: prep bf16 weights (replicated) + lastpos + msgb ---------
__global__ void k_initprep(const float* __restrict__ Wih, const float* __restrict__ Whh,
                           const float* __restrict__ Wk, const float* __restrict__ Wv,
                           const float* __restrict__ Wq, const float* __restrict__ We,
                           const float* __restrict__ Wskip,
                           const float* __restrict__ Wls, const float* __restrict__ Wld,
                           const int* __restrict__ src, const int* __restrict__ dst,
                           const float* __restrict__ msg,
                           unsigned short* __restrict__ wgru,
                           unsigned short* __restrict__ wattn,
                           unsigned short* __restrict__ wskp,
                           unsigned short* __restrict__ wlink,
                           unsigned short* __restrict__ msgb,
                           int* __restrict__ last_pos, int* __restrict__ count) {
    int idx = blockIdx.x * 256 + threadIdx.x;
    if (idx == 0) *count = 0;
    if (idx < 2 * NE) {                           // fused lastpos (pos+1 encoding)
        int id = (idx < NE) ? src[idx] : dst[idx - NE];
        atomicMax(&last_pos[id], idx + 1);
    }
    if (idx >= CVT0) {                            // dense msg -> bf16 stream
        int j = idx - CVT0;
        if (j < MSGB_V4) {
            float4 v = ((const float4*)msg)[j];
            ushort4 b;
            b.x = f2bf(v.x); b.y = f2bf(v.y); b.z = f2bf(v.z); b.w = f2bf(v.w);
            ((ushort4*)msgb)[j] = b;
        }
        return;
    }
    float4 v;
    unsigned short* dstp;
    int ncopies, stride;
    if (idx < 49152) {                            // gru
        int n = idx / 96;
        int c = (idx - n * 96) * 4;
        if (n < 384) {
            v = *(const float4*)&Wih[n * 384 + c];
            if (n < 256 && c < 128) {
                const float4 w2 = *(const float4*)&Whh[n * 128 + c];
                v.x += w2.x; v.y += w2.y; v.z += w2.z; v.w += w2.w;
            }
        } else {
            if (c >= 128) return;
            v = *(const float4*)&Whh[(n - 128) * 128 + c];
        }
        dstp = &wgru[n * 384 + c]; ncopies = 8; stride = WGRU_SZ;
    } else if (idx < 49152 + 36864) {             // attn
        int i2 = idx - 49152;
        int n = i2 / 96;
        int c = (i2 - n * 96) * 4;
        if (n < 256) {
            const float* Wm = (n < 128) ? Wk : Wv;
            int nn = n & 127;
            if (c < 128)       v = *(const float4*)&Wm[nn * 128 + c];
            else if (c < 256)  v = *(const float4*)&We[nn * 128 + (c - 128)];
            else return;
        } else {
            if (c < 256) return;
            v = *(const float4*)&Wq[(n - 256) * 128 + (c - 256)];
        }
        dstp = &wattn[n * 384 + c]; ncopies = 4; stride = WATTN_SZ;
    } else if (idx < 49152 + 36864 + 4096) {      // skip
        int i3 = idx - 49152 - 36864;
        int n = i3 / 32;
        int c = (i3 - n * 32) * 4;
        v = *(const float4*)&Wskip[n * 128 + c];
        dstp = &wskp[n * 128 + c]; ncopies = 8; stride = WSKP_SZ;
    } else {                                      // link: [Wls | Wld]
        int i4 = idx - 49152 - 36864 - 4096;
        int n = i4 / 64;
        int c = (i4 - n * 64) * 4;
        if (c < 128) v = *(const float4*)&Wls[n * 128 + c];
        else         v = *(const float4*)&Wld[n * 128 + (c - 128)];
        dstp = &wlink[n * 256 + c]; ncopies = 4; stride = WLINK_SZ;
    }
    ushort4 b;
    b.x = f2bf(v.x); b.y = f2bf(v.y); b.z = f2bf(v.z); b.w = f2bf(v.w);
    for (int r = 0; r < ncopies; ++r)
        *(ushort4*)(dstp + (size_t)r * stride) = b;
}

// ---------------- kernel 2: compact (cheap) ---------------------------------------
__global__ void k_compact(const int* __restrict__ src, const int* __restrict__ dst,
                          const int* __restrict__ last_pos,
                          const float* __restrict__ tp, const float* __restrict__ lup,
                          int* __restrict__ count, int* __restrict__ node2slot,
                          int* __restrict__ head,
                          int4* __restrict__ slot_aux,
                          float* __restrict__ lu_new) {
    int i = blockIdx.x * blockDim.x + threadIdx.x;
    if (i >= 2 * NE) return;
    int e  = (i < NE) ? i : i - NE;
    int id = (i < NE) ? src[e] : dst[e];
    if (last_pos[id] != i + 1) return;             // pos+1 encoding
    int s = atomicAdd(count, 1);
    node2slot[id] = s;
    head[s] = -1;                                  // edge-list head init (slot owner)
    int oth = (i < NE) ? dst[e] : src[e];
    float tt = tp[e];
    float lu = lup[id];
    lu_new[id] = fmaxf(lu, tt);
    int4 aux; aux.x = e; aux.y = oth; aux.z = __float_as_int(tt - lu); aux.w = id;
    slot_aux[s] = aux;
}

// ---------------- kernel 3: GRU GEMM, FAT BLOCK: GMB=128, 512 threads ---------------
// Two 64-row tiles interleaved in ONE GEMM loop: each B fragment loaded once from L2
// feeds 8 MFMAs (was 4). Halves B-panel L2 traffic (480->240MB) — the largest modeled
// pipe cost — and doubles MFMA work per b-load latency window. LDS 100KB, 1 block/CU,
// 8 waves/CU (acc[8][4]=128 AGPR + ~60 arch -> 2 waves/SIMD).
#define GMB 128
__global__ __launch_bounds__(512) void k_gru(
    const float* __restrict__ memp,
    const unsigned short* __restrict__ msgb,
    const float* __restrict__ twp, const float* __restrict__ tbp,
    const int4* __restrict__ slot_aux,
    const unsigned short* __restrict__ wgru_all,
    const float* __restrict__ bih, const float* __restrict__ bhh,
    const unsigned short* __restrict__ wskp_all, const float* __restrict__ bskip,
    const int* __restrict__ countp,
    unsigned short* __restrict__ mem_new, unsigned short* __restrict__ zbf)
{
    __shared__ alignas(16) unsigned short Xs[128][392];  // ~100 KB
    int cnt = *countp;
    int base = blockIdx.x * GMB;
    if (base >= cnt) return;
    int tid = threadIdx.x;
    const unsigned short* __restrict__ wgru = wgru_all + (size_t)(blockIdx.x & 7) * WGRU_SZ;
    const unsigned short* __restrict__ wskp = wskp_all + (size_t)(blockIdx.x & 7) * WSKP_SZ;

    {   // pack: 8 lanes per row, 2 halves of 64 rows each
        int m0 = tid >> 3, li = tid & 7;
        #pragma unroll
        for (int hh = 0; hh < 2; ++hh) {
            int m = m0 + hh * 64;
            int ii = base + m; if (ii >= cnt) ii = cnt - 1;   // tail dup (harmless)
            const int4 aux = slot_aux[ii];                    // dense 16B
            int e = aux.x, oth = aux.y, id = aux.w;
            float dt = __int_as_float(aux.z);
            const float4* idr  = (const float4*)(memp + (size_t)id  * D);
            const float4* othr = (const float4*)(memp + (size_t)oth * D);
            #pragma unroll
            for (int s4 = 0; s4 < 4; ++s4) {
                float4 v = idr[li + 8 * s4];
                ushort4 b;
                b.x = f2bf(v.x); b.y = f2bf(v.y); b.z = f2bf(v.z); b.w = f2bf(v.w);
                *(ushort4*)&Xs[m][(li + 8 * s4) * 4] = b;
                float4 v2 = othr[li + 8 * s4];
                ushort4 b2;
                b2.x = f2bf(v2.x); b2.y = f2bf(v2.y); b2.z = f2bf(v2.z); b2.w = f2bf(v2.w);
                *(ushort4*)&Xs[m][128 + (li + 8 * s4) * 4] = b2;
            }
            *(uint4*)&Xs[m][256 + li * 8] = *(const uint4*)&msgb[e * 64 + li * 8];
            int c0 = li * 8;
            float cv[8];
            #pragma unroll
            for (int k = 0; k < 8; ++k)
                cv[k] = cosf(dt * twp[c0 + k] + tbp[c0 + k]);
            ushort4 t0, t1;
            t0.x = f2bf(cv[0]); t0.y = f2bf(cv[1]); t0.z = f2bf(cv[2]); t0.w = f2bf(cv[3]);
            t1.x = f2bf(cv[4]); t1.y = f2bf(cv[5]); t1.z = f2bf(cv[6]); t1.w = f2bf(cv[7]);
            *(ushort4*)&Xs[m][320 + c0]     = t0;
            *(ushort4*)&Xs[m][320 + c0 + 4] = t1;
        }
    }
    __syncthreads();

    int lane = tid & 63, w = tid >> 6;
    int q = lane >> 4, l15 = lane & 15;
    int q8 = q * 8, w16 = w * 16;

    f32x4 acc[8][4];
    #pragma unroll
    for (int mt = 0; mt < 8; ++mt)
        #pragma unroll
        for (int g = 0; g < 4; ++g)
            acc[mt][g] = (f32x4)(0.0f);

#define GRU_STEP(NG)                                                                      \
    {                                                                                     \
        bf16x8 a[8];                                                                      \
        _Pragma("unroll")                                                                 \
        for (int mt = 0; mt < 8; ++mt) a[mt] = *(const bf16x8*)&Xs[mt * 16 + l15][k0 + q8]; \
        _Pragma("unroll")                                                                 \
        for (int g = 0; g < NG; ++g) {                                                    \
            const bf16x8 b = *(const bf16x8*)&wgru[(g * 128 + w16 + l15) * 384 + k0 + q8]; \
            _Pragma("unroll")                                                             \
            for (int mt = 0; mt < 8; ++mt)                                                \
                acc[mt][g] = __builtin_amdgcn_mfma_f32_16x16x32_bf16(a[mt], b, acc[mt][g], 0, 0, 0); \
        }                                                                                 \
    }

    #pragma unroll 2
    for (int ks = 0; ks < 4; ++ks) { int k0 = ks * 32; GRU_STEP(4) }
    #pragma unroll 2
    for (int ks = 4; ks < 12; ++ks) { int k0 = ks * 32; GRU_STEP(3) }
#undef GRU_STEP

    float nval[8][4];
    {
        int c = w16 + l15;
        float br  = bih[c]       + bhh[c];
        float bz  = bih[128 + c] + bhh[128 + c];
        float bin = bih[256 + c];
        float bhn = bhh[256 + c];
        #pragma unroll
        for (int mt = 0; mt < 8; ++mt) {
            #pragma unroll
            for (int reg = 0; reg < 4; ++reg) {
                int m = mt * 16 + q * 4 + reg;
                float r  = fsig_(acc[mt][0][reg] + br);
                float zg = fsig_(acc[mt][1][reg] + bz);
                float n  = ftanh_(acc[mt][2][reg] + bin + r * (acc[mt][3][reg] + bhn));
                float hv = bf2f(Xs[m][c]);
                nval[mt][reg] = (1.f - zg) * n + zg * hv;
            }
        }
    }

    __syncthreads();
    {
        int c = w16 + l15;
        #pragma unroll
        for (int mt = 0; mt < 8; ++mt)
            #pragma unroll
            for (int reg = 0; reg < 4; ++reg)
                Xs[mt * 16 + q * 4 + reg][c] = f2bf(nval[mt][reg]);
    }
    __syncthreads();

    {
        #pragma unroll
        for (int j = 0; j < 4; ++j) {
            int ch = tid + 512 * j;
            int m = ch >> 4, c8 = ch & 15;
            *(uint4*)&mem_new[(size_t)(base + m) * D + c8 * 8] = *(const uint4*)&Xs[m][c8 * 8];
        }
    }

    f32x4 acc2[8];
    #pragma unroll
    for (int mt = 0; mt < 8; ++mt) acc2[mt] = (f32x4)(0.0f);
    #pragma unroll
    for (int ks = 0; ks < 4; ++ks) {
        int k0 = ks * 32;
        bf16x8 a[8];
        #pragma unroll
        for (int mt = 0; mt < 8; ++mt) a[mt] = *(const bf16x8*)&Xs[mt * 16 + l15][k0 + q8];
        const bf16x8 b = *(const bf16x8*)&wskp[(w16 + l15) * 128 + k0 + q8];
        #pragma unroll
        for (int mt = 0; mt < 8; ++mt)
            acc2[mt] = __builtin_amdgcn_mfma_f32_16x16x32_bf16(a[mt], b, acc2[mt], 0, 0, 0);
    }
    __syncthreads();
    {
        int ch = w16 + l15;
        float b = bskip[ch];
        #pragma unroll
        for (int mt = 0; mt < 8; ++mt)
            #pragma unroll
            for (int reg = 0; reg < 4; ++reg)
                Xs[mt * 16 + q * 4 + reg][ch] = f2bf(acc2[mt][reg] + b);
    }
    __syncthreads();
    {
        #pragma unroll
        for (int j = 0; j < 4; ++j) {
            int ch = tid + 512 * j;
            int m = ch >> 4, c8 = ch & 15;
            *(uint4*)&zbf[(size_t)(base + m) * D + c8 * 8] = *(const uint4*)&Xs[m][c8 * 8];
        }
    }
}

// ---------------- kernel 5: attn M=64, 512 threads (unchanged from R8) --------------
#define AMB 64
__global__ __launch_bounds__(512) void k_attnA(
    const int* __restrict__ srcp, const int* __restrict__ dstp,
    const float* __restrict__ tp, const unsigned short* __restrict__ msgb,
    const float* __restrict__ twp, const float* __restrict__ tbp,
    const float* __restrict__ lu_new, const int* __restrict__ node2slot,
    const unsigned short* __restrict__ mem_new,
    const unsigned short* __restrict__ wattn_all,
    const float* __restrict__ bq, const float* __restrict__ bk, const float* __restrict__ bv,
    unsigned short* __restrict__ vbuf, float* __restrict__ abuf,
    int* __restrict__ head, int* __restrict__ next)
{
    __shared__ alignas(16) unsigned short Xs[64][392];        // 50,176 B
    unsigned short (*kLb)[136] = (unsigned short(*)[136])(&Xs[0][0]);           // 64x136
    unsigned short (*qLb)[136] = (unsigned short(*)[136])(&Xs[0][0] + 8704);    // 64x136
    __shared__ float sa[AMB][2];
    __shared__ int sslot[AMB], sdslot[AMB];
    __shared__ float srel[AMB];
    int tid = threadIdx.x;
    int e0 = blockIdx.x * AMB;
    const unsigned short* __restrict__ wattn = wattn_all + (size_t)(blockIdx.x & 3) * WATTN_SZ;
    {   // fused edge-chain build (head inited in k_compact)
        int gid = blockIdx.x * 512 + tid;
        if (gid < NE) {
            int sl = node2slot[dstp[gid]];
            next[gid] = atomicExch(&head[sl], gid);
        }
    }
    if (tid < AMB) {
        int e = e0 + tid; if (e >= NE) e = NE - 1;
        int s = srcp[e], dd = dstp[e];
        sslot[tid]  = node2slot[s];
        sdslot[tid] = node2slot[dd];
        srel[tid] = lu_new[s] - tp[e];
    }
    __syncthreads();
    {   // pack: 8 lanes/row, 64 rows: [src_mem | time_enc | msg | dst_mem]
        int m = tid >> 3, li = tid & 7;
        int e = e0 + m; if (e >= NE) e = NE - 1;
        int ssl = sslot[m], dsl = sdslot[m];
        float rel = srel[m];
        uint4* xrow = (uint4*)&Xs[m][0];
        const uint4* srow = (const uint4*)&mem_new[(size_t)ssl * D];
        const uint4* drow = (const uint4*)&mem_new[(size_t)dsl * D];
        #pragma unroll
        for (int j = 0; j < 2; ++j) {
            xrow[li + 8 * j]      = srow[li + 8 * j];
            xrow[32 + li + 8 * j] = drow[li + 8 * j];
        }
        {
            int c0 = li * 8;
            ushort4 lo, hi;
            lo.x = f2bf(cosf(rel * twp[c0 + 0] + tbp[c0 + 0]));
            lo.y = f2bf(cosf(rel * twp[c0 + 1] + tbp[c0 + 1]));
            lo.z = f2bf(cosf(rel * twp[c0 + 2] + tbp[c0 + 2]));
            lo.w = f2bf(cosf(rel * twp[c0 + 3] + tbp[c0 + 3]));
            hi.x = f2bf(cosf(rel * twp[c0 + 4] + tbp[c0 + 4]));
            hi.y = f2bf(cosf(rel * twp[c0 + 5] + tbp[c0 + 5]));
            hi.z = f2bf(cosf(rel * twp[c0 + 6] + tbp[c0 + 6]));
            hi.w = f2bf(cosf(rel * twp[c0 + 7] + tbp[c0 + 7]));
            *(ushort4*)&Xs[m][128 + c0]     = lo;
            *(ushort4*)&Xs[m][128 + c0 + 4] = hi;
        }
        *(uint4*)&Xs[m][192 + li * 8] = *(const uint4*)&msgb[e * 64 + li * 8];
    }
    __syncthreads();

    int lane = tid & 63, w = tid >> 6;          // 8 waves
    int q = lane >> 4, l15 = lane & 15;
    int q8 = q * 8;

    f32x4 acc[4][3];                             // [mt][gate]
    #pragma unroll
    for (int mt = 0; mt < 4; ++mt)
        #pragma unroll
        for (int jj = 0; jj < 3; ++jj) acc[mt][jj] = (f32x4)(0.0f);

    #pragma unroll 2
    for (int ks = 0; ks < 8; ++ks) {             // K,V gates consume X[0:256]
        int k0 = ks * 32;
        bf16x8 a[4];
        #pragma unroll
        for (int mt = 0; mt < 4; ++mt) a[mt] = *(const bf16x8*)&Xs[mt * 16 + l15][k0 + q8];
        #pragma unroll
        for (int jj = 0; jj < 2; ++jj) {
            int nt = w + 8 * jj;
            const bf16x8 b = *(const bf16x8*)&wattn[(nt * 16 + l15) * 384 + k0 + q8];
            #pragma unroll
            for (int mt = 0; mt < 4; ++mt)
                acc[mt][jj] = __builtin_amdgcn_mfma_f32_16x16x32_bf16(a[mt], b, acc[mt][jj], 0, 0, 0);
        }
    }
    #pragma unroll 2
    for (int ks = 8; ks < 12; ++ks) {            // Q gate consumes X[256:384]
        int k0 = ks * 32;
        bf16x8 a[4];
        #pragma unroll
        for (int mt = 0; mt < 4; ++mt) a[mt] = *(const bf16x8*)&Xs[mt * 16 + l15][k0 + q8];
        int nt = 16 + w;
        const bf16x8 b = *(const bf16x8*)&wattn[(nt * 16 + l15) * 384 + k0 + q8];
        #pragma unroll
        for (int mt = 0; mt < 4; ++mt)
            acc[mt][2] = __builtin_amdgcn_mfma_f32_16x16x32_bf16(a[mt], b, acc[mt][2], 0, 0, 0);
    }

    __syncthreads();    // Xs dead; kLb/qLb alias it — wait for all waves' K-loop reads

    float vreg[4][4];
    {
        int ch = w * 16 + l15;
        #pragma unroll
        for (int jj = 0; jj < 3; ++jj) {
            float bias = (jj == 0) ? bk[ch] : (jj == 1) ? bv[ch] : bq[ch];
            #pragma unroll
            for (int mt = 0; mt < 4; ++mt)
                #pragma unroll
                for (int reg = 0; reg < 4; ++reg) {
                    int m = mt * 16 + q * 4 + reg;
                    float val = acc[mt][jj][reg] + bias;
                    if (jj == 0)      kLb[m][ch] = f2bf(val);
                    else if (jj == 2) qLb[m][ch] = f2bf(val);
                    else              vreg[mt][reg] = val;
                }
        }
    }
    __syncthreads();
    #pragma unroll
    for (int pr = 0; pr < 16; ++pr) {            // 128 = 64 rows x 2 heads over 8 waves
        int p2 = pr * 8 + w;
        int m = p2 >> 1, h = p2 & 1;
        float prod = bf2f(qLb[m][h * 64 + lane]) * bf2f(kLb[m][h * 64 + lane]);
        #pragma unroll
        for (int off = 32; off; off >>= 1) prod += __shfl_down(prod, off);
        if (lane == 0) {
            float a = __expf(prod * 0.125f);
            sa[m][h] = a;
            if (e0 + m < NE) abuf[(e0 + m) * 2 + h] = a;
        }
    }
    __syncthreads();
    {
        unsigned short (*vL)[136] = qLb;         // qLb reads done (sync above)
        int ch = w * 16 + l15;
        int h = w >> 2;                          // this wave's head
        #pragma unroll
        for (int mt = 0; mt < 4; ++mt)
            #pragma unroll
            for (int reg = 0; reg < 4; ++reg) {
                int m = mt * 16 + q * 4 + reg;
                vL[m][ch] = f2bf(sa[m][h] * vreg[mt][reg]);
            }
        __syncthreads();
        #pragma unroll
        for (int j = 0; j < 2; ++j) {
            int chunk = tid + 512 * j;
            int row = chunk >> 4, c8 = chunk & 15;
            if (e0 + row < NE)
                *(uint4*)&vbuf[(size_t)(e0 + row) * D + c8 * 8] = *(const uint4*)&vL[row][c8 * 8];
        }
    }
}

// ---------------- kernel 6: gather per-dst-slot edge lists, normalize, z += ----------
__global__ __launch_bounds__(256) void k_gather(
    const int* __restrict__ countp, const int* __restrict__ head,
    const int* __restrict__ next, const float* __restrict__ abuf,
    const unsigned short* __restrict__ vbuf, unsigned short* __restrict__ zbf)
{
    int cnt = *countp;
    int slot = blockIdx.x * 32 + (threadIdx.x >> 3);
    if (slot >= cnt) return;
    int li = threadIdx.x & 7;
    int c0 = li * 16;
    int h = li >> 2;
    float vsum[16];
    #pragma unroll
    for (int j = 0; j < 16; ++j) vsum[j] = 0.f;
    float asum = 0.f;
    for (int e = head[slot]; e != -1; e = next[e]) {
        asum += abuf[e * 2 + h];
        uint4 v0 = *(const uint4*)&vbuf[(size_t)e * D + c0];
        uint4 v1 = *(const uint4*)&vbuf[(size_t)e * D + c0 + 8];
        const unsigned short* pv0 = (const unsigned short*)&v0;
        const unsigned short* pv1 = (const unsigned short*)&v1;
        #pragma unroll
        for (int j = 0; j < 8; ++j) { vsum[j] += bf2f(pv0[j]); vsum[8 + j] += bf2f(pv1[j]); }
    }
    if (asum > 0.f) {
        float rr = frcp_(asum);
        uint4 z0 = *(const uint4*)&zbf[(size_t)slot * D + c0];
        uint4 z1 = *(const uint4*)&zbf[(size_t)slot * D + c0 + 8];
        const unsigned short* pz0 = (const unsigned short*)&z0;
        const unsigned short* pz1 = (const unsigned short*)&z1;
        unsigned short o[16];
        #pragma unroll
        for (int j = 0; j < 8; ++j) {
            o[j]     = f2bf(bf2f(pz0[j]) + vsum[j] * rr);
            o[8 + j] = f2bf(bf2f(pz1[j]) + vsum[8 + j] * rr);
        }
        *(uint4*)&zbf[(size_t)slot * D + c0]     = *(const uint4*)&o[0];
        *(uint4*)&zbf[(size_t)slot * D + c0 + 8] = *(const uint4*)&o[8];
    }
}

// ---------------- kernel 7: link predictor, K=256, M=32 (R1-best config) -------------
#define ALB 32
__global__ __launch_bounds__(256) void k_link(
    const int* __restrict__ srcp, const int* __restrict__ dstp,
    const int* __restrict__ node2slot,
    const unsigned short* __restrict__ zbf,
    const unsigned short* __restrict__ wlink_all,
    const float* __restrict__ bls, const float* __restrict__ bld,
    const float* __restrict__ Wlf, const float* __restrict__ blf,
    float* __restrict__ outp)
{
    __shared__ alignas(16) unsigned short Xs[32][264];
    __shared__ int ssl[32], sdl[32];
    __shared__ float sred[32][4];
    int tid = threadIdx.x;
    int e0 = blockIdx.x * ALB;
    const unsigned short* __restrict__ wlink = wlink_all + (size_t)(blockIdx.x & 3) * WLINK_SZ;
    if (tid < ALB) {
        int e = e0 + tid; if (e >= NE) e = NE - 1;
        ssl[tid] = node2slot[srcp[e]];
        sdl[tid] = node2slot[dstp[e]];
    }
    __syncthreads();
    {
        int m = tid >> 3, li = tid & 7;
        uint4* xrow = (uint4*)&Xs[m][0];
        const uint4* srow = (const uint4*)&zbf[(size_t)ssl[m] * D];
        const uint4* drow = (const uint4*)&zbf[(size_t)sdl[m] * D];
        xrow[li]      = srow[li];
        xrow[li + 8]  = srow[li + 8];
        xrow[16 + li] = drow[li];
        xrow[24 + li] = drow[li + 8];
    }
    __syncthreads();

    int lane = tid & 63, w = tid >> 6;
    int q = lane >> 4, l15 = lane & 15;
    int q8 = q * 8;

    f32x4 acc[2][2];
    #pragma unroll
    for (int mt = 0; mt < 2; ++mt)
        #pragma unroll
        for (int jj = 0; jj < 2; ++jj) acc[mt][jj] = (f32x4)(0.0f);

    #pragma unroll
    for (int ks = 0; ks < 8; ++ks) {
        int k0 = ks * 32;
        const bf16x8 a0 = *(const bf16x8*)&Xs[l15][k0 + q8];
        const bf16x8 a1 = *(const bf16x8*)&Xs[16 + l15][k0 + q8];
        #pragma unroll
        for (int jj = 0; jj < 2; ++jj) {
            int nt = w + 4 * jj;
            const bf16x8 b = *(const bf16x8*)&wlink[(nt * 16 + l15) * 256 + k0 + q8];
            acc[0][jj] = __builtin_amdgcn_mfma_f32_16x16x32_bf16(a0, b, acc[0][jj], 0, 0, 0);
            acc[1][jj] = __builtin_amdgcn_mfma_f32_16x16x32_bf16(a1, b, acc[1][jj], 0, 0, 0);
        }
    }

    float p[2][4];
    #pragma unroll
    for (int mt = 0; mt < 2; ++mt)
        #pragma unroll
        for (int reg = 0; reg < 4; ++reg) p[mt][reg] = 0.f;
    #pragma unroll
    for (int jj = 0; jj < 2; ++jj) {
        int ch = (w + 4 * jj) * 16 + l15;
        float bias = bls[ch] + bld[ch];
        float wl = Wlf[ch];
        #pragma unroll
        for (int mt = 0; mt < 2; ++mt)
            #pragma unroll
            for (int reg = 0; reg < 4; ++reg)
                p[mt][reg] += fmaxf(acc[mt][jj][reg] + bias, 0.f) * wl;
    }
    #pragma unroll
    for (int mask = 1; mask < 16; mask <<= 1) {
        #pragma unroll
        for (int mt = 0; mt < 2; ++mt)
            #pragma unroll
            for (int reg = 0; reg < 4; ++reg)
                p[mt][reg] += __shfl_xor(p[mt][reg], mask);
    }
    if (l15 == 0) {
        #pragma unroll
        for (int mt = 0; mt < 2; ++mt)
            #pragma unroll
            for (int reg = 0; reg < 4; ++reg)
                sred[mt * 16 + q * 4 + reg][w] = p[mt][reg];
    }
    __syncthreads();
    if (tid < ALB) {
        int e = e0 + tid;
        if (e < NE)
            outp[e] = sred[tid][0] + sred[tid][1] + sred[tid][2] + sred[tid][3] + blf[0];
    }
}

extern "C" void kernel_launch(void* const* d_in, const int* in_sizes, int n_in,
                              void* d_out, int out_size, void* d_ws, size_t ws_size,
                              hipStream_t stream)
{
    const float* memory      = (const float*)d_in[0];
    const float* last_update = (const float*)d_in[1];
    const float* t           = (const float*)d_in[2];
    const float* msg         = (const float*)d_in[3];
    const int*   src         = (const int*)d_in[4];
    const int*   dst         = (const int*)d_in[5];
    const float* time_w      = (const float*)d_in[6];
    const float* time_b      = (const float*)d_in[7];
    const float* gru_Wih     = (const float*)d_in[8];
    const float* gru_bih     = (const float*)d_in[9];
    const float* gru_Whh     = (const float*)d_in[10];
    const float* gru_bhh     = (const float*)d_in[11];
    const float* Wq          = (const float*)d_in[12];
    const float* bq          = (const float*)d_in[13];
    const float* Wk          = (const float*)d_in[14];
    const float* bk          = (const float*)d_in[15];
    const float* Wv          = (const float*)d_in[16];
    const float* bv          = (const float*)d_in[17];
    const float* We          = (const float*)d_in[18];
    const float* Wskip       = (const float*)d_in[19];
    const float* bskip       = (const float*)d_in[20];
    const float* Wls         = (const float*)d_in[21];
    const float* bls         = (const float*)d_in[22];
    const float* Wld         = (const float*)d_in[23];
    const float* bld         = (const float*)d_in[24];
    const float* Wlf         = (const float*)d_in[25];
    const float* blf         = (const float*)d_in[26];
    float* outp = (float*)d_out;

    // workspace layout (bytes); R = 100,032 slots; weights replicated for L2 spread
    char* ws = (char*)d_ws;
    int*   last_pos  = (int*)  (ws + 0);               // N (pos+1 encoding, no init)
    int*   node2slot = (int*)  (ws + 800000);          // N
    float* lu_new    = (float*)(ws + 1600000);         // N
    int*   count     = (int*)  (ws + 2400000);         // 1 (+pad)
    int4*  slot_aux  = (int4*) (ws + 2400016);         // R x {e, oth, dt, id}
    unsigned short* msgb    = (unsigned short*)(ws + 4000528);   // 50k*64 bf16
    unsigned short* wgru    = (unsigned short*)(ws + 10400528);  // 8 x 512*384 bf16
    unsigned short* wattn   = (unsigned short*)(ws + 13546256);  // 4 x 384*384 bf16
    unsigned short* wskp    = (unsigned short*)(ws + 14725904);  // 8 x 128*128 bf16
    unsigned short* wlink   = (unsigned short*)(ws + 14988048);  // 4 x 128*256 bf16
    unsigned short* mem_new = (unsigned short*)(ws + 15250192);  // R*128 bf16 (by slot)
    unsigned short* zbf     = (unsigned short*)(ws + 40858384);  // R*128 bf16 (by slot)
    unsigned short* vbuf    = (unsigned short*)(ws + 66466576);  // E*128 bf16 (by edge)
    float* abuf = (float*)(ws + 79266576);             // E*2 f32 (by edge)
    int*   head = (int*)  (ws + 79666576);             // R int (by slot)
    int*   next = (int*)  (ws + 80066704);             // E int (by edge)

    k_initprep<<<(CVT0 + MSGB_V4 + 255) / 256, 256, 0, stream>>>(
                 gru_Wih, gru_Whh, Wk, Wv, Wq, We, Wskip, Wls, Wld, src, dst, msg,
                 wgru, wattn, wskp, wlink, msgb, last_pos, count);
    k_compact <<<(2 * NE + 255) / 256, 256, 0, stream>>>(src, dst, last_pos,
                 t, last_update, count, node2slot, head, slot_aux, lu_new);
    k_gru     <<<(2 * NE + GMB - 1) / GMB, 512, 0, stream>>>(memory, msgb, time_w, time_b,
                 slot_aux, wgru, gru_bih, gru_bhh, wskp, bskip, count, mem_new, zbf);
    k_attnA   <<<(NE + AMB - 1) / AMB, 512, 0, stream>>>(src, dst, t, msgb, time_w, time_b,
                 lu_new, node2slot, mem_new, wattn, bq, bk, bv, vbuf, abuf, head, next);
    k_gather  <<<(2 * NE + 31) / 32, 256, 0, stream>>>(count, head, next, abuf, vbuf, zbf);
    k_link    <<<(NE + ALB - 1) / ALB, 256, 0, stream>>>(src, dst, node2slot, zbf,
                 wlink, bls, bld, Wlf, blf, outp);
}